// Round 17
// baseline (419.912 us; speedup 1.0000x reference)
//
#include <hip/hip_runtime.h>
#include <hip/hip_bf16.h>
#include <hip/hip_fp16.h>
#include <math.h>

#define VOCAB 50000
#define FEAT 300
#define KPAD 320
#define HID 512
#define C 20
#define NL 2
#define NH 4
#define KHOP 3
#define ALPHA 0.1f
#define NNODE 76800
#define NEDGE 1250000
#define NB 512
#define SLOPE 0.2f

#define NBKT 300
#define BKTCAP 5120
#define NSLOT (NBKT * BKTCAP)
#define EPB 5120
#define NEBLK ((NEDGE + EPB - 1) / EPB)   // 245

#define BM 32
#define VPAD 50048          // 1564 * 32
#define SX_STRIDE 520
#define WSTRIDE 21          // padded LDS stride for transposed W (bank spread)
#define RW 24               // row width in halves: [z(20) | es | ed | 0 | 0]

typedef float f32x4 __attribute__((ext_vector_type(4)));
typedef short bf16x8 __attribute__((ext_vector_type(8)));

__device__ inline unsigned short f2b(float x) {
  __hip_bfloat16 h = __float2bfloat16(x);
  return *reinterpret_cast<unsigned short*>(&h);
}

// 48B row of fp16 (24 halves, 16B-aligned; slots 20/21 carry es/ed)
union R24 {
  uint4 u[3];
  __half2 h[12];
  __half s[24];
};
__device__ inline R24 ldrow24(const __half* p) {
  R24 r;
  r.u[0] = *(const uint4*)p;
  r.u[1] = *(const uint4*)(p + 8);
  r.u[2] = *(const uint4*)(p + 16);
  return r;
}
__device__ inline void strow24(__half* p, const R24& r) {
  *(uint4*)p = r.u[0];
  *(uint4*)(p + 8) = r.u[1];
  *(uint4*)(p + 16) = r.u[2];
}

// single-instruction cross-lane xor swizzles (bitmode: (xor<<10)|0x1F)
#define H2SWZ(v, pat) ({ union { __half2 h; int i; } _u; _u.h = (v);          \
                         _u.i = __builtin_amdgcn_ds_swizzle(_u.i, (pat));     \
                         _u.h; })
#define FSWZ(x, pat) __int_as_float(                                          \
    __builtin_amdgcn_ds_swizzle(__float_as_int(x), (pat)))
// slot reduce: lanes differ in bits 2..4 -> xor 4, 8, 16
#define SLOTRED_H2(v) do {                                                    \
    v = __hadd2(v, H2SWZ(v, 0x101F));                                         \
    v = __hadd2(v, H2SWZ(v, 0x201F));                                         \
    v = __hadd2(v, H2SWZ(v, 0x401F)); } while (0)

// ---------------------------------------------------------------------------
// prep kernels
// ---------------------------------------------------------------------------
__global__ void k_cvt_w1(const float* __restrict__ W1, ushort* __restrict__ W1t)
{
  int idx = blockIdx.x * 256 + threadIdx.x;   // 40*512*8 = 163840
  int kc = idx >> 12;
  int rem = idx & 4095;
  int col = rem >> 3;
  int j = rem & 7;
  int k = kc * 8 + j;
  W1t[idx] = (k < FEAT) ? f2b(W1[(size_t)k * HID + col]) : (ushort)0;
}

__global__ void k_prep_coef(const float* __restrict__ gatW0,
                            const float* __restrict__ as0,
                            const float* __restrict__ ad0,
                            const float* __restrict__ b2,
                            float* __restrict__ coef, float* __restrict__ bb)
{
  int col = threadIdx.x;
  if (col >= 96) return;
  float cf[C];
  if (col < 80) {
    int hd = col / C, d = col - hd * C;
#pragma unroll
    for (int j = 0; j < C; j++) cf[j] = gatW0[(hd * C + j) * C + d];
  } else if (col < 88) {
    int hd = col - 80;
#pragma unroll
    for (int j = 0; j < C; j++) {
      float s = 0.f;
#pragma unroll
      for (int d = 0; d < C; d++) s += gatW0[(hd * C + j) * C + d] * as0[hd * C + d];
      cf[j] = s;
    }
  } else {
    int hd = col - 88;
#pragma unroll
    for (int j = 0; j < C; j++) {
      float s = 0.f;
#pragma unroll
      for (int d = 0; d < C; d++) s += gatW0[(hd * C + j) * C + d] * ad0[hd * C + d];
      cf[j] = s;
    }
  }
  float bbv = 0.f;
#pragma unroll
  for (int j = 0; j < C; j++) { coef[col * C + j] = cf[j]; bbv += b2[j] * cf[j]; }
  bb[col] = bbv;
}

__global__ void k_prep_wcp(const float* __restrict__ W2,
                           const float* __restrict__ coef,
                           ushort* __restrict__ Wcpt)
{
  int idx = blockIdx.x * 256 + threadIdx.x;   // 64*96*8 = 49152
  int kc = idx / 768;
  int rem = idx - kc * 768;
  int col = rem >> 3;
  int j = rem & 7;
  int k = kc * 8 + j;
  float s = 0.f;
#pragma unroll
  for (int jj = 0; jj < C; jj++) s += W2[(size_t)k * C + jj] * coef[col * C + jj];
  Wcpt[idx] = f2b(s);
}

// ---------------------------------------------------------------------------
// K1: per vocab row: x = relu(emb@W1+b1); [z(80) es(4) ed(4)] = x@Wc + bb
// rows: zfull[(v*4+h)*24 + {0..19:z, 20:es, 21:ed}]
// B fragments double-buffered in registers; launch_bounds(512,4).
// ---------------------------------------------------------------------------
__global__ __launch_bounds__(512, 4) void k_mlp_mfma(
    const float* __restrict__ emb, const ushort* __restrict__ W1t,
    const float* __restrict__ b1, const ushort* __restrict__ Wcpt,
    const float* __restrict__ bb, __half* __restrict__ zfull)
{
  __shared__ ushort smem[16640];   // 33.3KB: sA [40][32][8] (20KB) / sX [32][520]
  ushort* sA = smem;
  ushort* sX = smem;

  const int t = threadIdx.x;
  const int lane = t & 63;
  const int w = t >> 6;
  const int v0 = blockIdx.x * BM;
  const int l15 = lane & 15;
  const int l4 = lane >> 4;
  const int cb = w * 64;             // wave col base (64 distinct cols)

  // stage A: 1280 16B chunks, [kc][row][8], with on-the-fly f32->bf16
#pragma unroll
  for (int j = 0; j < 3; j++) {
    int chunk = j * 512 + t;
    if (chunk < 1280) {
      int row = chunk & 31;
      int kc = chunk >> 5;
      int vr = v0 + row;
      if (vr >= VOCAB) vr = VOCAB - 1;
      int k0 = kc * 8;
      const float* p = emb + (size_t)vr * FEAT + k0;
      ushort u[8];
      if (k0 + 8 <= FEAT) {
        float4 x = *(const float4*)p;
        float4 y = *(const float4*)(p + 4);
        u[0] = f2b(x.x); u[1] = f2b(x.y); u[2] = f2b(x.z); u[3] = f2b(x.w);
        u[4] = f2b(y.x); u[5] = f2b(y.y); u[6] = f2b(y.z); u[7] = f2b(y.w);
      } else {
#pragma unroll
        for (int q = 0; q < 8; q++)
          u[q] = (k0 + q < FEAT) ? f2b(p[q]) : (ushort)0;
      }
      *(uint4*)(sA + (size_t)chunk * 8) = *(const uint4*)u;
    }
  }
  __syncthreads();

  f32x4 acc[2][4];
#pragma unroll
  for (int rt = 0; rt < 2; rt++)
#pragma unroll
    for (int ct = 0; ct < 4; ct++) acc[rt][ct] = (f32x4)0.f;

  const ushort* wbase = W1t + ((size_t)l4 * 512 + cb + l15) * 8;
  bf16x8 bfA[4], bfB[4];
#define LOADB(DST, KS)                                                        \
  { _Pragma("unroll")                                                         \
    for (int ct = 0; ct < 4; ct++)                                            \
      DST[ct] = *(const bf16x8*)(wbase + (size_t)(KS) * 16384 + ct * 128); }
#define DOMFMA(BF, KS)                                                        \
  { const int kcb = (KS) * 4 + l4;                                            \
    bf16x8 a0 = *(const bf16x8*)(sA + ((size_t)kcb * 32 + l15) * 8);          \
    bf16x8 a1 = *(const bf16x8*)(sA + ((size_t)kcb * 32 + 16 + l15) * 8);     \
    _Pragma("unroll")                                                         \
    for (int ct = 0; ct < 4; ct++) {                                          \
      acc[0][ct] = __builtin_amdgcn_mfma_f32_16x16x32_bf16(a0, BF[ct],        \
                                                           acc[0][ct], 0, 0, 0);\
      acc[1][ct] = __builtin_amdgcn_mfma_f32_16x16x32_bf16(a1, BF[ct],        \
                                                           acc[1][ct], 0, 0, 0);\
    } }

  LOADB(bfA, 0);
#pragma unroll
  for (int ks2 = 0; ks2 < 10; ks2 += 2) {
    LOADB(bfB, ks2 + 1);
    DOMFMA(bfA, ks2);
    if (ks2 + 2 < 10) LOADB(bfA, ks2 + 2);
    DOMFMA(bfB, ks2 + 1);
  }
  __syncthreads();   // all sA reads done

  // x = relu(acc + b1) -> sX bf16 [32][520]
#pragma unroll
  for (int rt = 0; rt < 2; rt++)
#pragma unroll
    for (int ct = 0; ct < 4; ct++) {
      int col = cb + ct * 16 + l15;
      float bias = b1[col];
#pragma unroll
      for (int r4 = 0; r4 < 4; r4++) {
        int row = rt * 16 + l4 * 4 + r4;
        float x = fmaxf(acc[rt][ct][r4] + bias, 0.f);
        sX[(size_t)row * SX_STRIDE + col] = f2b(x);
      }
    }
  __syncthreads();

  // phase2: 12 tiles (2 rt x 6 ct); wave w does tile w, and 8+w if w<4
  const int ntile = (w < 4) ? 2 : 1;
  for (int i = 0; i < ntile; i++) {
    const int tt = (i == 0) ? w : 8 + w;
    const int rt = tt & 1, ct = tt >> 1;
    const ushort* xb = sX + (size_t)(rt * 16 + l15) * SX_STRIDE + l4 * 8;
    const ushort* wbp = Wcpt + ((size_t)l4 * 96 + ct * 16 + l15) * 8;
    bf16x8 bv[16];
#pragma unroll
    for (int ks = 0; ks < 16; ks++)
      bv[ks] = *(const bf16x8*)(wbp + (size_t)ks * 3072);   // kc += 4
    f32x4 a2 = (f32x4)0.f;
#pragma unroll
    for (int ks = 0; ks < 16; ks++) {
      bf16x8 av = *(const bf16x8*)(xb + ks * 32);
      a2 = __builtin_amdgcn_mfma_f32_16x16x32_bf16(av, bv[ks], a2, 0, 0, 0);
    }
    const int col = ct * 16 + l15;
    const float bias = bb[col];
#pragma unroll
    for (int r = 0; r < 4; r++) {
      const int vrow = v0 + rt * 16 + l4 * 4 + r;
      if (vrow >= VOCAB) continue;
      float val = a2[r] + bias;
      if (col < 80) {
        int hd = col / C, c = col - hd * C;
        zfull[((size_t)vrow * NH + hd) * RW + c] = __float2half_rn(val);
      } else if (col < 88) {
        zfull[((size_t)vrow * NH + (col - 80)) * RW + 20] = __float2half_rn(val);
      } else {
        zfull[((size_t)vrow * NH + (col - 88)) * RW + 21] = __float2half_rn(val);
      }
    }
  }
}

// ---------------------------------------------------------------------------
// CSR build: gapped buckets (fixed capacity)
// ---------------------------------------------------------------------------
__global__ __launch_bounds__(256) void k_bkt_scatter(
    const int* __restrict__ src, const int* __restrict__ dst,
    int* __restrict__ gcur, int* __restrict__ gbuf)
{
  __shared__ int hist[NBKT];
  __shared__ int lcur[NBKT];
  const int t = threadIdx.x;
  for (int i = t; i < NBKT; i += 256) hist[i] = 0;
  __syncthreads();
  const int base = blockIdx.x * EPB;
#pragma unroll
  for (int j = 0; j < 20; j++) {
    int e = base + j * 256 + t;
    if (e < NEDGE) atomicAdd(&hist[dst[e] >> 8], 1);
  }
  __syncthreads();
  for (int i = t; i < NBKT; i += 256) {
    int v = hist[i];
    lcur[i] = v ? atomicAdd(&gcur[i], v) : 0;
  }
  __syncthreads();
#pragma unroll
  for (int j = 0; j < 20; j++) {
    int e = base + j * 256 + t;
    if (e < NEDGE) {
      int d = dst[e];
      int b = d >> 8;
      int idx = atomicAdd(&lcur[b], 1);
      if (idx < BKTCAP)
        gbuf[(size_t)b * BKTCAP + idx] = (src[e] << 8) | (d & 255);
    }
  }
}

__global__ __launch_bounds__(256) void k_csr_build(
    const int* __restrict__ gcur, const int* __restrict__ gbuf,
    const int* __restrict__ node_ids, int* __restrict__ offs,
    int* __restrict__ deg, int* __restrict__ srcc, int* __restrict__ srcv)
{
  __shared__ int shist[256];
  __shared__ int lcur[256];
  __shared__ int wsum[4];
  const int b = blockIdx.x;
  const int t = threadIdx.x;
  const int base = b * BKTCAP;
  int nb = gcur[b];
  if (nb > BKTCAP) nb = BKTCAP;
  shist[t] = 0;
  __syncthreads();
  for (int i = t; i < nb; i += 256)
    atomicAdd(&shist[gbuf[base + i] & 255], 1);
  __syncthreads();
  int v = shist[t];
  int x = v;
#pragma unroll
  for (int off = 1; off < 64; off <<= 1) {
    int y = __shfl_up(x, off, 64);
    if ((t & 63) >= off) x += y;
  }
  if ((t & 63) == 63) wsum[t >> 6] = x;
  __syncthreads();
  int waveoff = 0;
#pragma unroll
  for (int w = 0; w < 4; w++) waveoff += (w < (t >> 6)) ? wsum[w] : 0;
  int pre = base + waveoff + x - v;
  offs[b * 256 + t] = pre;
  deg[b * 256 + t] = v;
  lcur[t] = pre;
  __syncthreads();
  for (int i = t; i < nb; i += 256) {
    int p = gbuf[base + i];
    int slot = atomicAdd(&lcur[p & 255], 1);
    int s = p >> 8;
    srcc[slot] = s;
    srcv[slot] = node_ids[s];
  }
}

// ---------------------------------------------------------------------------
// Hop kernels: 32 lanes/node (4 heads x 8 edge-slots), 8 nodes/block.
// 48B rows with es/ed packed (slots 20/21) -> hop_first needs NO extra gather.
// ---------------------------------------------------------------------------
__global__ __launch_bounds__(256) void k_hop_first(
    const int* __restrict__ offs, const int* __restrict__ deg,
    const int* __restrict__ sidx,
    const int* __restrict__ ids, const __half* __restrict__ Zt,
    __half* __restrict__ att, float* __restrict__ invden,
    __half* __restrict__ Hout)
{
  const int t = threadIdx.x;
  const int head = t & 3;
  const int eslot = (t >> 2) & 7;
  const int n = blockIdx.x * 8 + (t >> 5);
  const int g = n * NH + head;
  const int idn = ids ? ids[n] : n;
  const int beg = offs[n], end = beg + deg[n];
  R24 h0 = ldrow24(Zt + ((size_t)idn * NH + head) * RW);   // self row (has ed)
  const float edv = __half2float(h0.s[21]);
  __half2 agg[10];
#pragma unroll
  for (int q = 0; q < 10; q++) agg[q] = __floats2half2_rn(0.f, 0.f);
  float den = 0.f;
  int p = beg + eslot;
  while (p + 8 < end) {
    int sv0 = sidx[p];
    int sv1 = sidx[p + 8];
    R24 r0 = ldrow24(Zt + ((size_t)sv0 * NH + head) * RW);
    R24 r1 = ldrow24(Zt + ((size_t)sv1 * NH + head) * RW);
    float e0 = __half2float(r0.s[20]) + edv; e0 = e0 > 0.f ? e0 : SLOPE * e0;
    float e1 = __half2float(r1.s[20]) + edv; e1 = e1 > 0.f ? e1 : SLOPE * e1;
    float ex0 = __expf(e0), ex1 = __expf(e1);
    att[(size_t)p * NH + head] = __float2half_rn(ex0);
    att[(size_t)(p + 8) * NH + head] = __float2half_rn(ex1);
    den += ex0 + ex1;
    __half2 a0 = __float2half2_rn(ex0);
    __half2 a1 = __float2half2_rn(ex1);
#pragma unroll
    for (int q = 0; q < 10; q++) {
      agg[q] = __hfma2(a0, r0.h[q], agg[q]);
      agg[q] = __hfma2(a1, r1.h[q], agg[q]);
    }
    p += 16;
  }
  if (p < end) {
    int sv0 = sidx[p];
    R24 r0 = ldrow24(Zt + ((size_t)sv0 * NH + head) * RW);
    float e0 = __half2float(r0.s[20]) + edv; e0 = e0 > 0.f ? e0 : SLOPE * e0;
    float ex0 = __expf(e0);
    att[(size_t)p * NH + head] = __float2half_rn(ex0);
    den += ex0;
    __half2 a0 = __float2half2_rn(ex0);
#pragma unroll
    for (int q = 0; q < 10; q++) agg[q] = __hfma2(a0, r0.h[q], agg[q]);
  }
#pragma unroll
  for (int q = 0; q < 10; q++) SLOTRED_H2(agg[q]);
  den += FSWZ(den, 0x101F);
  den += FSWZ(den, 0x201F);
  den += FSWZ(den, 0x401F);
  if (eslot == 0) {
    float inv = 1.f / (den + 1e-9f);
    invden[g] = inv;
    __half2 s2 = __float2half2_rn(inv * (1.0f - ALPHA));
    __half2 al = __float2half2_rn(ALPHA);
    R24 o;
#pragma unroll
    for (int q = 0; q < 10; q++)
      o.h[q] = __hfma2(s2, agg[q], __hmul2(al, h0.h[q]));
    o.h[10] = __floats2half2_rn(0.f, 0.f);
    o.h[11] = o.h[10];
    strow24(Hout + (size_t)g * RW, o);
  }
}

__global__ __launch_bounds__(256) void k_hop_mid(
    const int* __restrict__ offs, const int* __restrict__ deg,
    const int* __restrict__ srcc,
    const __half* __restrict__ att, const float* __restrict__ invden,
    const __half* __restrict__ Hin, const __half* __restrict__ Zt,
    const int* __restrict__ ids, __half* __restrict__ Hout)
{
  const int t = threadIdx.x;
  const int head = t & 3;
  const int eslot = (t >> 2) & 7;
  const int n = blockIdx.x * 8 + (t >> 5);
  const int g = n * NH + head;
  const int idn = ids ? ids[n] : n;
  const int beg = offs[n], end = beg + deg[n];
  R24 h0 = ldrow24(Zt + ((size_t)idn * NH + head) * RW);   // hoisted self-row
  __half2 agg[10];
#pragma unroll
  for (int q = 0; q < 10; q++) agg[q] = __floats2half2_rn(0.f, 0.f);
  int p = beg + eslot;
  while (p + 8 < end) {
    __half a0h = att[(size_t)p * NH + head];
    __half a1h = att[(size_t)(p + 8) * NH + head];
    int sn0 = srcc[p];
    int sn1 = srcc[p + 8];
    R24 r0 = ldrow24(Hin + ((size_t)sn0 * NH + head) * RW);
    R24 r1 = ldrow24(Hin + ((size_t)sn1 * NH + head) * RW);
    __half2 a0 = __half2half2(a0h);
    __half2 a1 = __half2half2(a1h);
#pragma unroll
    for (int q = 0; q < 10; q++) {
      agg[q] = __hfma2(a0, r0.h[q], agg[q]);
      agg[q] = __hfma2(a1, r1.h[q], agg[q]);
    }
    p += 16;
  }
  if (p < end) {
    __half a0h = att[(size_t)p * NH + head];
    int sn0 = srcc[p];
    R24 r0 = ldrow24(Hin + ((size_t)sn0 * NH + head) * RW);
    __half2 a0 = __half2half2(a0h);
#pragma unroll
    for (int q = 0; q < 10; q++) agg[q] = __hfma2(a0, r0.h[q], agg[q]);
  }
#pragma unroll
  for (int q = 0; q < 10; q++) SLOTRED_H2(agg[q]);
  if (eslot == 0) {
    __half2 s2 = __float2half2_rn(invden[g] * (1.0f - ALPHA));
    __half2 al = __float2half2_rn(ALPHA);
    R24 o;
#pragma unroll
    for (int q = 0; q < 10; q++)
      o.h[q] = __hfma2(s2, agg[q], __hmul2(al, h0.h[q]));
    o.h[10] = __floats2half2_rn(0.f, 0.f);
    o.h[11] = o.h[10];
    strow24(Hout + (size_t)g * RW, o);
  }
}

// ---------------------------------------------------------------------------
// Layer-0 last hop FUSED with layer-1 GAT projection.
// Writes zb rows WITH es/ed packed (slots 20/21).
// ---------------------------------------------------------------------------
__global__ __launch_bounds__(256) void k_hop_last_proj(
    const int* __restrict__ offs, const int* __restrict__ deg,
    const int* __restrict__ srcc,
    const __half* __restrict__ att, const float* __restrict__ invden,
    const __half* __restrict__ Hin, const __half* __restrict__ Zt,
    const int* __restrict__ ids,
    const float* __restrict__ gatW1, const float* __restrict__ as1,
    const float* __restrict__ ad1, __half* __restrict__ zb)
{
  __shared__ float sWt[NH * C * WSTRIDE];   // [h][d][21]
  __shared__ float sa[NH * C], sd[NH * C];
  const int t = threadIdx.x;
  for (int i = t; i < NH * C * C; i += 256) {
    int h = i / (C * C);
    int r = i - h * C * C;
    int c = r / C;
    int d = r - c * C;
    sWt[(h * C + d) * WSTRIDE + c] = gatW1[i];
  }
  if (t < NH * C) { sa[t] = as1[t]; sd[t] = ad1[t]; }
  __syncthreads();

  const int head = t & 3;
  const int eslot = (t >> 2) & 7;
  const int n = blockIdx.x * 8 + (t >> 5);
  const int g = n * NH + head;
  const int idn = ids ? ids[n] : n;
  const int beg = offs[n], end = beg + deg[n];
  R24 h0 = ldrow24(Zt + ((size_t)idn * NH + head) * RW);   // hoisted self-row
  __half2 agg[10];
#pragma unroll
  for (int q = 0; q < 10; q++) agg[q] = __floats2half2_rn(0.f, 0.f);
  int p = beg + eslot;
  while (p + 8 < end) {
    __half a0h = att[(size_t)p * NH + head];
    __half a1h = att[(size_t)(p + 8) * NH + head];
    int sn0 = srcc[p];
    int sn1 = srcc[p + 8];
    R24 r0 = ldrow24(Hin + ((size_t)sn0 * NH + head) * RW);
    R24 r1 = ldrow24(Hin + ((size_t)sn1 * NH + head) * RW);
    __half2 a0 = __half2half2(a0h);
    __half2 a1 = __half2half2(a1h);
#pragma unroll
    for (int q = 0; q < 10; q++) {
      agg[q] = __hfma2(a0, r0.h[q], agg[q]);
      agg[q] = __hfma2(a1, r1.h[q], agg[q]);
    }
    p += 16;
  }
  if (p < end) {
    __half a0h = att[(size_t)p * NH + head];
    int sn0 = srcc[p];
    R24 r0 = ldrow24(Hin + ((size_t)sn0 * NH + head) * RW);
    __half2 a0 = __half2half2(a0h);
#pragma unroll
    for (int q = 0; q < 10; q++) agg[q] = __hfma2(a0, r0.h[q], agg[q]);
  }
#pragma unroll
  for (int q = 0; q < 10; q++) SLOTRED_H2(agg[q]);

  // all lanes: combine, head-mean, ELU -> full h vector in f32
  __half2 s2 = __float2half2_rn(invden[g] * (1.0f - ALPHA));
  __half2 al = __float2half2_rn(ALPHA);
  float o[C];
#pragma unroll
  for (int q = 0; q < 10; q++) {
    __half2 m = __hfma2(s2, agg[q], __hmul2(al, h0.h[q]));
    m = __hadd2(m, H2SWZ(m, 0x041F));   // + head^1
    m = __hadd2(m, H2SWZ(m, 0x081F));   // + head^2
    float2 f = __half22float2(m);
    float v0 = f.x * 0.25f, v1 = f.y * 0.25f;
    o[2 * q]     = v0 > 0.f ? v0 : __expf(v0) - 1.f;
    o[2 * q + 1] = v1 > 0.f ? v1 : __expf(v1) - 1.f;
  }

  // distributed projection: slot s handles d = s, s+8, s+16 (<20)
  float esp = 0.f, edp = 0.f;
  __half* zrow = zb + ((size_t)n * NH + head) * RW;
#pragma unroll
  for (int j = 0; j < 3; j++) {
    int d = eslot + j * 8;
    if (d < C) {
      const float* wrow = &sWt[(head * C + d) * WSTRIDE];
      float zv = 0.f;
#pragma unroll
      for (int c = 0; c < C; c++) zv += o[c] * wrow[c];
      esp += zv * sa[head * C + d];
      edp += zv * sd[head * C + d];
      zrow[d] = __float2half_rn(zv);
    }
  }
  esp += FSWZ(esp, 0x101F);
  esp += FSWZ(esp, 0x201F);
  esp += FSWZ(esp, 0x401F);
  edp += FSWZ(edp, 0x101F);
  edp += FSWZ(edp, 0x201F);
  edp += FSWZ(edp, 0x401F);
  if (eslot == 0) {
    zrow[20] = __float2half_rn(esp);
    zrow[21] = __float2half_rn(edp);
  }
}

#define RSPAN 16
__global__ __launch_bounds__(256) void k_hop_last_final(
    const int* __restrict__ offs, const int* __restrict__ deg,
    const int* __restrict__ srcc,
    const __half* __restrict__ att, const float* __restrict__ invden,
    const __half* __restrict__ Hin, const __half* __restrict__ Zt,
    const int* __restrict__ gids, const float* __restrict__ wsW,
    const float* __restrict__ wsb, float* __restrict__ out)
{
  __shared__ float sacc[RSPAN * C];
  __shared__ int sgmin;
  const int t = threadIdx.x;
  const int head = t & 3;
  const int eslot = (t >> 2) & 7;
  const int n = blockIdx.x * 8 + (t >> 5);
  const int g = n * NH + head;
  const int beg = offs[n], end = beg + deg[n];
  for (int i = t; i < RSPAN * C; i += 256) sacc[i] = 0.f;
  if (t == 0) sgmin = gids[blockIdx.x * 8];
  __syncthreads();
  R24 h0 = ldrow24(Zt + ((size_t)n * NH + head) * RW);     // hoisted self-row
  __half2 agg[10];
#pragma unroll
  for (int q = 0; q < 10; q++) agg[q] = __floats2half2_rn(0.f, 0.f);
  int p = beg + eslot;
  while (p + 8 < end) {
    __half a0h = att[(size_t)p * NH + head];
    __half a1h = att[(size_t)(p + 8) * NH + head];
    int sn0 = srcc[p];
    int sn1 = srcc[p + 8];
    R24 r0 = ldrow24(Hin + ((size_t)sn0 * NH + head) * RW);
    R24 r1 = ldrow24(Hin + ((size_t)sn1 * NH + head) * RW);
    __half2 a0 = __half2half2(a0h);
    __half2 a1 = __half2half2(a1h);
#pragma unroll
    for (int q = 0; q < 10; q++) {
      agg[q] = __hfma2(a0, r0.h[q], agg[q]);
      agg[q] = __hfma2(a1, r1.h[q], agg[q]);
    }
    p += 16;
  }
  if (p < end) {
    __half a0h = att[(size_t)p * NH + head];
    int sn0 = srcc[p];
    R24 r0 = ldrow24(Hin + ((size_t)sn0 * NH + head) * RW);
    __half2 a0 = __half2half2(a0h);
#pragma unroll
    for (int q = 0; q < 10; q++) agg[q] = __hfma2(a0, r0.h[q], agg[q]);
  }
#pragma unroll
  for (int q = 0; q < 10; q++) SLOTRED_H2(agg[q]);
  if (eslot == 0) {
    __half2 s2 = __float2half2_rn(invden[g] * (1.0f - ALPHA));
    __half2 al = __float2half2_rn(ALPHA);
    float o[C];
#pragma unroll
    for (int q = 0; q < 10; q++) {
      __half2 m = __hfma2(s2, agg[q], __hmul2(al, h0.h[q]));
      m = __hadd2(m, H2SWZ(m, 0x041F));
      m = __hadd2(m, H2SWZ(m, 0x081F));
      float2 f = __half22float2(m);
      o[2 * q]     = f.x * 0.25f;
      o[2 * q + 1] = f.y * 0.25f;
    }
    // distributed gate dot: partial on own 5 channels, reduce over heads
    float dotp = 0.f;
#pragma unroll
    for (int j = 0; j < 5; j++) {
      int c = head * 5 + j;
      dotp += o[c] * wsW[c];
    }
    dotp += FSWZ(dotp, 0x041F);
    dotp += FSWZ(dotp, 0x081F);
    const float gate = 1.f / (1.f + __expf(-(dotp + wsb[0])));
    const int b = gids[n];
    const int lb = b - sgmin;
    if (lb < RSPAN) {
#pragma unroll
      for (int j = 0; j < 5; j++) {
        int c = head * 5 + j;
        atomicAdd(&sacc[lb * C + c], o[c] * gate);
      }
    } else {
#pragma unroll
      for (int j = 0; j < 5; j++) {
        int c = head * 5 + j;
        atomicAdd(&out[(size_t)b * C + c], o[c] * gate);
      }
    }
  }
  __syncthreads();
  for (int i = t; i < RSPAN * C; i += 256) {
    float v = sacc[i];
    if (v != 0.f) atomicAdd(&out[(size_t)(sgmin + i / C) * C + (i - (i / C) * C)], v);
  }
}

// ---------------------------------------------------------------------------
extern "C" void kernel_launch(void* const* d_in, const int* in_sizes, int n_in,
                              void* d_out, int out_size, void* d_ws, size_t ws_size,
                              hipStream_t stream)
{
  const int*   node_ids = (const int*)  d_in[0];
  const int*   edge_src = (const int*)  d_in[1];
  const int*   edge_dst = (const int*)  d_in[2];
  const int*   graph_ids= (const int*)  d_in[3];
  const float* emb      = (const float*)d_in[4];
  const float* W1       = (const float*)d_in[5];
  const float* b1       = (const float*)d_in[6];
  const float* W2       = (const float*)d_in[7];
  const float* b2       = (const float*)d_in[8];
  const float* gat_W    = (const float*)d_in[9];
  const float* gat_asrc = (const float*)d_in[10];
  const float* gat_adst = (const float*)d_in[11];
  const float* ws_W     = (const float*)d_in[12];
  const float* ws_b     = (const float*)d_in[13];
  float* out = (float*)d_out;

  // ---- workspace (~70 MB). X region time-shared: gbuf -> att ----
  float* invden = (float*)d_ws;                      // NH*NNODE
  float* bb     = invden + (size_t)NNODE * NH;       // 96
  float* coef   = bb + 96;                           // 96*20
  int*   offs   = (int*)(coef + 96 * C);             // N
  int*   deg    = offs + NNODE;                      // N
  int*   gcur   = deg + NNODE;                       // 300
  int*   srcc   = gcur + NBKT;                       // NSLOT
  int*   srcv   = srcc + NSLOT;                      // NSLOT
  uintptr_t a16 = ((uintptr_t)(srcv + NSLOT) + 15) & ~(uintptr_t)15;
  __half* zfull = (__half*)a16;                      // VPAD*NH*24
  __half* zb    = zfull + (size_t)VPAD * NH * RW;    // N*NH*24
  __half* bufA  = zb    + (size_t)NNODE * NH * RW;
  __half* bufB  = bufA  + (size_t)NNODE * NH * RW;
  ushort* W1t   = (ushort*)(bufB + (size_t)NNODE * NH * RW);  // 40*512*8
  ushort* Wcpt  = W1t + (size_t)40 * 512 * 8;        // 64*96*8
  uintptr_t x16 = ((uintptr_t)(Wcpt + 64 * 96 * 8) + 15) & ~(uintptr_t)15;
  int*    gbuf  = (int*)x16;                         // X: NSLOT ints
  __half* att   = (__half*)x16;                      // X: NH*NSLOT halves

  hipMemsetAsync(out, 0, (size_t)NB * C * sizeof(float), stream);
  hipMemsetAsync(gcur, 0, NBKT * sizeof(int), stream);

  // prep
  k_cvt_w1<<<(40 * 512 * 8) / 256, 256, 0, stream>>>(W1, W1t);
  k_prep_coef<<<1, 128, 0, stream>>>(gat_W, gat_asrc, gat_adst, b2, coef, bb);
  k_prep_wcp<<<(64 * 96 * 8) / 256, 256, 0, stream>>>(W2, coef, Wcpt);

  // CSR build (gapped buckets; X: gbuf)
  k_bkt_scatter<<<NEBLK, 256, 0, stream>>>(edge_src, edge_dst, gcur, gbuf);
  k_csr_build<<<NBKT, 256, 0, stream>>>(gcur, gbuf, node_ids,
                                        offs, deg, srcc, srcv);

  // MLP + folded layer-0 GAT projection (reads f32 emb directly)
  k_mlp_mfma<<<VPAD / BM, 512, 0, stream>>>(emb, W1t, b1, Wcpt, bb, zfull);

  const int HB = NNODE / 8;   // 9600 blocks for hop kernels (X: att)
  // layer 0 (vocab-space z); last hop fused with layer-1 projection
  k_hop_first<<<HB, 256, 0, stream>>>(offs, deg, srcv, node_ids,
                                      zfull, att, invden, bufA);
  k_hop_mid<<<HB, 256, 0, stream>>>(offs, deg, srcc, att, invden, bufA, zfull,
                                    node_ids, bufB);
  k_hop_last_proj<<<HB, 256, 0, stream>>>(offs, deg, srcc, att, invden, bufB,
                                          zfull, node_ids,
                                          gat_W + (size_t)NH * C * C,
                                          gat_asrc + NH * C, gat_adst + NH * C,
                                          zb);
  // layer 1
  k_hop_first<<<HB, 256, 0, stream>>>(offs, deg, srcc, (const int*)nullptr,
                                      zb, att, invden, bufA);
  k_hop_mid<<<HB, 256, 0, stream>>>(offs, deg, srcc, att, invden, bufA, zb,
                                    (const int*)nullptr, bufB);
  k_hop_last_final<<<HB, 256, 0, stream>>>(offs, deg, srcc, att, invden, bufB,
                                           zb, graph_ids, ws_W, ws_b, out);
}

// Round 18
// 407.303 us; speedup vs baseline: 1.0310x; 1.0310x over previous
//
#include <hip/hip_runtime.h>
#include <hip/hip_bf16.h>
#include <hip/hip_fp16.h>
#include <math.h>

#define VOCAB 50000
#define FEAT 300
#define KPAD 320
#define HID 512
#define C 20
#define NL 2
#define NH 4
#define KHOP 3
#define ALPHA 0.1f
#define NNODE 76800
#define NEDGE 1250000
#define NB 512
#define SLOPE 0.2f

#define NBKT 300
#define BKTCAP 5120
#define NSLOT (NBKT * BKTCAP)
#define EPB 5120
#define NEBLK ((NEDGE + EPB - 1) / EPB)   // 245

#define BM 32
#define VPAD 50048          // 1564 * 32
#define SX_STRIDE 520
#define WSTRIDE 21          // padded LDS stride for transposed W (bank spread)

typedef float f32x4 __attribute__((ext_vector_type(4)));
typedef short bf16x8 __attribute__((ext_vector_type(8)));

__device__ inline unsigned short f2b(float x) {
  __hip_bfloat16 h = __float2bfloat16(x);
  return *reinterpret_cast<unsigned short*>(&h);
}

// 40B row of fp16 (exactly 20 halves, 8B-aligned)
union R20 {
  struct { uint4 a, b; uint2 c; } v;
  __half2 h[10];
};
__device__ inline R20 ldrow20(const __half* p) {
  R20 r;
  r.v.a = *(const uint4*)p;
  r.v.b = *(const uint4*)(p + 8);
  r.v.c = *(const uint2*)(p + 16);
  return r;
}
__device__ inline void strow20(__half* p, const R20& r) {
  *(uint4*)p = r.v.a;
  *(uint4*)(p + 8) = r.v.b;
  *(uint2*)(p + 16) = r.v.c;
}

// single-instruction cross-lane xor swizzles (bitmode: (xor<<10)|0x1F)
#define H2SWZ(v, pat) ({ union { __half2 h; int i; } _u; _u.h = (v);          \
                         _u.i = __builtin_amdgcn_ds_swizzle(_u.i, (pat));     \
                         _u.h; })
#define FSWZ(x, pat) __int_as_float(                                          \
    __builtin_amdgcn_ds_swizzle(__float_as_int(x), (pat)))
// slot reduce: lanes differ in bits 2..4 -> xor 4, 8, 16
#define SLOTRED_H2(v) do {                                                    \
    v = __hadd2(v, H2SWZ(v, 0x101F));                                         \
    v = __hadd2(v, H2SWZ(v, 0x201F));                                         \
    v = __hadd2(v, H2SWZ(v, 0x401F)); } while (0)

// ---------------------------------------------------------------------------
// prep kernels
// ---------------------------------------------------------------------------
__global__ void k_cvt_w1(const float* __restrict__ W1, ushort* __restrict__ W1t)
{
  int idx = blockIdx.x * 256 + threadIdx.x;   // 40*512*8 = 163840
  int kc = idx >> 12;
  int rem = idx & 4095;
  int col = rem >> 3;
  int j = rem & 7;
  int k = kc * 8 + j;
  W1t[idx] = (k < FEAT) ? f2b(W1[(size_t)k * HID + col]) : (ushort)0;
}

__global__ void k_prep_coef(const float* __restrict__ gatW0,
                            const float* __restrict__ as0,
                            const float* __restrict__ ad0,
                            const float* __restrict__ b2,
                            float* __restrict__ coef, float* __restrict__ bb)
{
  int col = threadIdx.x;
  if (col >= 96) return;
  float cf[C];
  if (col < 80) {
    int hd = col / C, d = col - hd * C;
#pragma unroll
    for (int j = 0; j < C; j++) cf[j] = gatW0[(hd * C + j) * C + d];
  } else if (col < 88) {
    int hd = col - 80;
#pragma unroll
    for (int j = 0; j < C; j++) {
      float s = 0.f;
#pragma unroll
      for (int d = 0; d < C; d++) s += gatW0[(hd * C + j) * C + d] * as0[hd * C + d];
      cf[j] = s;
    }
  } else {
    int hd = col - 88;
#pragma unroll
    for (int j = 0; j < C; j++) {
      float s = 0.f;
#pragma unroll
      for (int d = 0; d < C; d++) s += gatW0[(hd * C + j) * C + d] * ad0[hd * C + d];
      cf[j] = s;
    }
  }
  float bbv = 0.f;
#pragma unroll
  for (int j = 0; j < C; j++) { coef[col * C + j] = cf[j]; bbv += b2[j] * cf[j]; }
  bb[col] = bbv;
}

__global__ void k_prep_wcp(const float* __restrict__ W2,
                           const float* __restrict__ coef,
                           ushort* __restrict__ Wcpt)
{
  int idx = blockIdx.x * 256 + threadIdx.x;   // 64*96*8 = 49152
  int kc = idx / 768;
  int rem = idx - kc * 768;
  int col = rem >> 3;
  int j = rem & 7;
  int k = kc * 8 + j;
  float s = 0.f;
#pragma unroll
  for (int jj = 0; jj < C; jj++) s += W2[(size_t)k * C + jj] * coef[col * C + jj];
  Wcpt[idx] = f2b(s);
}

// ---------------------------------------------------------------------------
// K1: per vocab row: x = relu(emb@W1+b1); [z(80) es(4) ed(4)] = x@Wc + bb
// z written in packed-20 layout: zfull[(v*4+h)*20 + c]
// B fragments register double-buffered; launch_bounds(512,6) keeps 3 blk/CU.
// ---------------------------------------------------------------------------
__global__ __launch_bounds__(512, 6) void k_mlp_mfma(
    const float* __restrict__ emb, const ushort* __restrict__ W1t,
    const float* __restrict__ b1, const ushort* __restrict__ Wcpt,
    const float* __restrict__ bb, __half* __restrict__ zfull,
    float* __restrict__ esf, float* __restrict__ edf)
{
  __shared__ ushort smem[16640];   // 33.3KB: sA [40][32][8] (20KB) / sX [32][520]
  ushort* sA = smem;
  ushort* sX = smem;

  const int t = threadIdx.x;
  const int lane = t & 63;
  const int w = t >> 6;
  const int v0 = blockIdx.x * BM;
  const int l15 = lane & 15;
  const int l4 = lane >> 4;
  const int cb = w * 64;             // wave col base (64 distinct cols)

  // stage A: 1280 16B chunks, [kc][row][8], with on-the-fly f32->bf16
#pragma unroll
  for (int j = 0; j < 3; j++) {
    int chunk = j * 512 + t;
    if (chunk < 1280) {
      int row = chunk & 31;
      int kc = chunk >> 5;
      int vr = v0 + row;
      if (vr >= VOCAB) vr = VOCAB - 1;
      int k0 = kc * 8;
      const float* p = emb + (size_t)vr * FEAT + k0;
      ushort u[8];
      if (k0 + 8 <= FEAT) {
        float4 x = *(const float4*)p;
        float4 y = *(const float4*)(p + 4);
        u[0] = f2b(x.x); u[1] = f2b(x.y); u[2] = f2b(x.z); u[3] = f2b(x.w);
        u[4] = f2b(y.x); u[5] = f2b(y.y); u[6] = f2b(y.z); u[7] = f2b(y.w);
      } else {
#pragma unroll
        for (int q = 0; q < 8; q++)
          u[q] = (k0 + q < FEAT) ? f2b(p[q]) : (ushort)0;
      }
      *(uint4*)(sA + (size_t)chunk * 8) = *(const uint4*)u;
    }
  }
  __syncthreads();

  f32x4 acc[2][4];
#pragma unroll
  for (int rt = 0; rt < 2; rt++)
#pragma unroll
    for (int ct = 0; ct < 4; ct++) acc[rt][ct] = (f32x4)0.f;

  const ushort* wbase = W1t + ((size_t)l4 * 512 + cb + l15) * 8;
  bf16x8 bfA[4], bfB[4];
#define LOADB(DST, KS)                                                        \
  { _Pragma("unroll")                                                         \
    for (int ct = 0; ct < 4; ct++)                                            \
      DST[ct] = *(const bf16x8*)(wbase + (size_t)(KS) * 16384 + ct * 128); }
#define DOMFMA(BF, KS)                                                        \
  { const int kcb = (KS) * 4 + l4;                                            \
    bf16x8 a0 = *(const bf16x8*)(sA + ((size_t)kcb * 32 + l15) * 8);          \
    bf16x8 a1 = *(const bf16x8*)(sA + ((size_t)kcb * 32 + 16 + l15) * 8);     \
    _Pragma("unroll")                                                         \
    for (int ct = 0; ct < 4; ct++) {                                          \
      acc[0][ct] = __builtin_amdgcn_mfma_f32_16x16x32_bf16(a0, BF[ct],        \
                                                           acc[0][ct], 0, 0, 0);\
      acc[1][ct] = __builtin_amdgcn_mfma_f32_16x16x32_bf16(a1, BF[ct],        \
                                                           acc[1][ct], 0, 0, 0);\
    } }

  LOADB(bfA, 0);
#pragma unroll
  for (int ks2 = 0; ks2 < 10; ks2 += 2) {
    LOADB(bfB, ks2 + 1);
    DOMFMA(bfA, ks2);
    if (ks2 + 2 < 10) LOADB(bfA, ks2 + 2);
    DOMFMA(bfB, ks2 + 1);
  }
  __syncthreads();   // all sA reads done

  // x = relu(acc + b1) -> sX bf16 [32][520]
#pragma unroll
  for (int rt = 0; rt < 2; rt++)
#pragma unroll
    for (int ct = 0; ct < 4; ct++) {
      int col = cb + ct * 16 + l15;
      float bias = b1[col];
#pragma unroll
      for (int r4 = 0; r4 < 4; r4++) {
        int row = rt * 16 + l4 * 4 + r4;
        float x = fmaxf(acc[rt][ct][r4] + bias, 0.f);
        sX[(size_t)row * SX_STRIDE + col] = f2b(x);
      }
    }
  __syncthreads();

  // phase2: 12 tiles (2 rt x 6 ct); wave w does tile w, and 8+w if w<4
  const int ntile = (w < 4) ? 2 : 1;
  for (int i = 0; i < ntile; i++) {
    const int tt = (i == 0) ? w : 8 + w;
    const int rt = tt & 1, ct = tt >> 1;
    const ushort* xb = sX + (size_t)(rt * 16 + l15) * SX_STRIDE + l4 * 8;
    const ushort* wbp = Wcpt + ((size_t)l4 * 96 + ct * 16 + l15) * 8;
    bf16x8 bv[16];
#pragma unroll
    for (int ks = 0; ks < 16; ks++)
      bv[ks] = *(const bf16x8*)(wbp + (size_t)ks * 3072);   // kc += 4
    f32x4 a2 = (f32x4)0.f;
#pragma unroll
    for (int ks = 0; ks < 16; ks++) {
      bf16x8 av = *(const bf16x8*)(xb + ks * 32);
      a2 = __builtin_amdgcn_mfma_f32_16x16x32_bf16(av, bv[ks], a2, 0, 0, 0);
    }
    const int col = ct * 16 + l15;
    const float bias = bb[col];
#pragma unroll
    for (int r = 0; r < 4; r++) {
      const int vrow = v0 + rt * 16 + l4 * 4 + r;
      if (vrow >= VOCAB) continue;
      float val = a2[r] + bias;
      if (col < 80) {
        int hd = col / C, c = col - hd * C;
        zfull[((size_t)vrow * NH + hd) * 20 + c] = __float2half_rn(val);
      } else if (col < 88) {
        esf[(size_t)vrow * NH + (col - 80)] = val;
      } else {
        edf[(size_t)vrow * NH + (col - 88)] = val;
      }
    }
  }
}

// ---------------------------------------------------------------------------
// CSR build: gapped buckets (fixed capacity)
// ---------------------------------------------------------------------------
__global__ __launch_bounds__(256) void k_bkt_scatter(
    const int* __restrict__ src, const int* __restrict__ dst,
    int* __restrict__ gcur, int* __restrict__ gbuf)
{
  __shared__ int hist[NBKT];
  __shared__ int lcur[NBKT];
  const int t = threadIdx.x;
  for (int i = t; i < NBKT; i += 256) hist[i] = 0;
  __syncthreads();
  const int base = blockIdx.x * EPB;
#pragma unroll
  for (int j = 0; j < 20; j++) {
    int e = base + j * 256 + t;
    if (e < NEDGE) atomicAdd(&hist[dst[e] >> 8], 1);
  }
  __syncthreads();
  for (int i = t; i < NBKT; i += 256) {
    int v = hist[i];
    lcur[i] = v ? atomicAdd(&gcur[i], v) : 0;
  }
  __syncthreads();
#pragma unroll
  for (int j = 0; j < 20; j++) {
    int e = base + j * 256 + t;
    if (e < NEDGE) {
      int d = dst[e];
      int b = d >> 8;
      int idx = atomicAdd(&lcur[b], 1);
      if (idx < BKTCAP)
        gbuf[(size_t)b * BKTCAP + idx] = (src[e] << 8) | (d & 255);
    }
  }
}

__global__ __launch_bounds__(256) void k_csr_build(
    const int* __restrict__ gcur, const int* __restrict__ gbuf,
    const int* __restrict__ node_ids, int* __restrict__ offs,
    int* __restrict__ deg, int* __restrict__ srcc, int* __restrict__ srcv)
{
  __shared__ int shist[256];
  __shared__ int lcur[256];
  __shared__ int wsum[4];
  const int b = blockIdx.x;
  const int t = threadIdx.x;
  const int base = b * BKTCAP;
  int nb = gcur[b];
  if (nb > BKTCAP) nb = BKTCAP;
  shist[t] = 0;
  __syncthreads();
  for (int i = t; i < nb; i += 256)
    atomicAdd(&shist[gbuf[base + i] & 255], 1);
  __syncthreads();
  int v = shist[t];
  int x = v;
#pragma unroll
  for (int off = 1; off < 64; off <<= 1) {
    int y = __shfl_up(x, off, 64);
    if ((t & 63) >= off) x += y;
  }
  if ((t & 63) == 63) wsum[t >> 6] = x;
  __syncthreads();
  int waveoff = 0;
#pragma unroll
  for (int w = 0; w < 4; w++) waveoff += (w < (t >> 6)) ? wsum[w] : 0;
  int pre = base + waveoff + x - v;
  offs[b * 256 + t] = pre;
  deg[b * 256 + t] = v;
  lcur[t] = pre;
  __syncthreads();
  for (int i = t; i < nb; i += 256) {
    int p = gbuf[base + i];
    int slot = atomicAdd(&lcur[p & 255], 1);
    int s = p >> 8;
    srcc[slot] = s;
    srcv[slot] = node_ids[s];
  }
}

// ---------------------------------------------------------------------------
// Hop kernels: 32 lanes/node (4 heads x 8 edge-slots), 8 nodes/block.
// Packed 40B rows; 2-way unrolled gathers; swizzle reduces; hoisted h0.
// ---------------------------------------------------------------------------
__global__ __launch_bounds__(256) void k_hop_first(
    const int* __restrict__ offs, const int* __restrict__ deg,
    const int* __restrict__ sidx,
    const float* __restrict__ esT, const float* __restrict__ edT,
    const int* __restrict__ ids, const __half* __restrict__ Zt,
    __half* __restrict__ att, float* __restrict__ invden,
    __half* __restrict__ Hout)
{
  const int t = threadIdx.x;
  const int head = t & 3;
  const int eslot = (t >> 2) & 7;
  const int n = blockIdx.x * 8 + (t >> 5);
  const int g = n * NH + head;
  const int idn = ids ? ids[n] : n;
  const int beg = offs[n], end = beg + deg[n];
  const float edv = edT[(size_t)idn * NH + head];
  R20 h0 = ldrow20(Zt + ((size_t)idn * NH + head) * 20);   // hoisted self-row
  __half2 agg[10];
#pragma unroll
  for (int q = 0; q < 10; q++) agg[q] = __floats2half2_rn(0.f, 0.f);
  float den = 0.f;
  int p = beg + eslot;
  while (p + 8 < end) {
    int sv0 = sidx[p];
    int sv1 = sidx[p + 8];
    float es0 = esT[(size_t)sv0 * NH + head];
    float es1 = esT[(size_t)sv1 * NH + head];
    R20 r0 = ldrow20(Zt + ((size_t)sv0 * NH + head) * 20);
    R20 r1 = ldrow20(Zt + ((size_t)sv1 * NH + head) * 20);
    float e0 = es0 + edv; e0 = e0 > 0.f ? e0 : SLOPE * e0;
    float e1 = es1 + edv; e1 = e1 > 0.f ? e1 : SLOPE * e1;
    float ex0 = __expf(e0), ex1 = __expf(e1);
    att[(size_t)p * NH + head] = __float2half_rn(ex0);
    att[(size_t)(p + 8) * NH + head] = __float2half_rn(ex1);
    den += ex0 + ex1;
    __half2 a0 = __float2half2_rn(ex0);
    __half2 a1 = __float2half2_rn(ex1);
#pragma unroll
    for (int q = 0; q < 10; q++) {
      agg[q] = __hfma2(a0, r0.h[q], agg[q]);
      agg[q] = __hfma2(a1, r1.h[q], agg[q]);
    }
    p += 16;
  }
  if (p < end) {
    int sv0 = sidx[p];
    float es0 = esT[(size_t)sv0 * NH + head];
    R20 r0 = ldrow20(Zt + ((size_t)sv0 * NH + head) * 20);
    float e0 = es0 + edv; e0 = e0 > 0.f ? e0 : SLOPE * e0;
    float ex0 = __expf(e0);
    att[(size_t)p * NH + head] = __float2half_rn(ex0);
    den += ex0;
    __half2 a0 = __float2half2_rn(ex0);
#pragma unroll
    for (int q = 0; q < 10; q++) agg[q] = __hfma2(a0, r0.h[q], agg[q]);
  }
#pragma unroll
  for (int q = 0; q < 10; q++) SLOTRED_H2(agg[q]);
  den += FSWZ(den, 0x101F);
  den += FSWZ(den, 0x201F);
  den += FSWZ(den, 0x401F);
  if (eslot == 0) {
    float inv = 1.f / (den + 1e-9f);
    invden[g] = inv;
    __half2 s2 = __float2half2_rn(inv * (1.0f - ALPHA));
    __half2 al = __float2half2_rn(ALPHA);
    R20 o;
#pragma unroll
    for (int q = 0; q < 10; q++)
      o.h[q] = __hfma2(s2, agg[q], __hmul2(al, h0.h[q]));
    strow20(Hout + (size_t)g * 20, o);
  }
}

__global__ __launch_bounds__(256) void k_hop_mid(
    const int* __restrict__ offs, const int* __restrict__ deg,
    const int* __restrict__ srcc,
    const __half* __restrict__ att, const float* __restrict__ invden,
    const __half* __restrict__ Hin, const __half* __restrict__ Zt,
    const int* __restrict__ ids, __half* __restrict__ Hout)
{
  const int t = threadIdx.x;
  const int head = t & 3;
  const int eslot = (t >> 2) & 7;
  const int n = blockIdx.x * 8 + (t >> 5);
  const int g = n * NH + head;
  const int idn = ids ? ids[n] : n;
  const int beg = offs[n], end = beg + deg[n];
  R20 h0 = ldrow20(Zt + ((size_t)idn * NH + head) * 20);   // hoisted self-row
  __half2 agg[10];
#pragma unroll
  for (int q = 0; q < 10; q++) agg[q] = __floats2half2_rn(0.f, 0.f);
  int p = beg + eslot;
  while (p + 8 < end) {
    __half a0h = att[(size_t)p * NH + head];
    __half a1h = att[(size_t)(p + 8) * NH + head];
    int sn0 = srcc[p];
    int sn1 = srcc[p + 8];
    R20 r0 = ldrow20(Hin + ((size_t)sn0 * NH + head) * 20);
    R20 r1 = ldrow20(Hin + ((size_t)sn1 * NH + head) * 20);
    __half2 a0 = __half2half2(a0h);
    __half2 a1 = __half2half2(a1h);
#pragma unroll
    for (int q = 0; q < 10; q++) {
      agg[q] = __hfma2(a0, r0.h[q], agg[q]);
      agg[q] = __hfma2(a1, r1.h[q], agg[q]);
    }
    p += 16;
  }
  if (p < end) {
    __half a0h = att[(size_t)p * NH + head];
    int sn0 = srcc[p];
    R20 r0 = ldrow20(Hin + ((size_t)sn0 * NH + head) * 20);
    __half2 a0 = __half2half2(a0h);
#pragma unroll
    for (int q = 0; q < 10; q++) agg[q] = __hfma2(a0, r0.h[q], agg[q]);
  }
#pragma unroll
  for (int q = 0; q < 10; q++) SLOTRED_H2(agg[q]);
  if (eslot == 0) {
    __half2 s2 = __float2half2_rn(invden[g] * (1.0f - ALPHA));
    __half2 al = __float2half2_rn(ALPHA);
    R20 o;
#pragma unroll
    for (int q = 0; q < 10; q++)
      o.h[q] = __hfma2(s2, agg[q], __hmul2(al, h0.h[q]));
    strow20(Hout + (size_t)g * 20, o);
  }
}

// ---------------------------------------------------------------------------
// Layer-0 last hop FUSED with layer-1 GAT projection.
// W1 transposed+padded in LDS: sWt[h][d][21] -> stride-1 c loop, bank-spread.
// ---------------------------------------------------------------------------
__global__ __launch_bounds__(256) void k_hop_last_proj(
    const int* __restrict__ offs, const int* __restrict__ deg,
    const int* __restrict__ srcc,
    const __half* __restrict__ att, const float* __restrict__ invden,
    const __half* __restrict__ Hin, const __half* __restrict__ Zt,
    const int* __restrict__ ids,
    const float* __restrict__ gatW1, const float* __restrict__ as1,
    const float* __restrict__ ad1,
    __half* __restrict__ zb, float* __restrict__ es, float* __restrict__ ed)
{
  __shared__ float sWt[NH * C * WSTRIDE];   // [h][d][21]
  __shared__ float sa[NH * C], sd[NH * C];
  const int t = threadIdx.x;
  for (int i = t; i < NH * C * C; i += 256) {
    int h = i / (C * C);
    int r = i - h * C * C;
    int c = r / C;
    int d = r - c * C;
    sWt[(h * C + d) * WSTRIDE + c] = gatW1[i];
  }
  if (t < NH * C) { sa[t] = as1[t]; sd[t] = ad1[t]; }
  __syncthreads();

  const int head = t & 3;
  const int eslot = (t >> 2) & 7;
  const int n = blockIdx.x * 8 + (t >> 5);
  const int g = n * NH + head;
  const int idn = ids ? ids[n] : n;
  const int beg = offs[n], end = beg + deg[n];
  R20 h0 = ldrow20(Zt + ((size_t)idn * NH + head) * 20);   // hoisted self-row
  __half2 agg[10];
#pragma unroll
  for (int q = 0; q < 10; q++) agg[q] = __floats2half2_rn(0.f, 0.f);
  int p = beg + eslot;
  while (p + 8 < end) {
    __half a0h = att[(size_t)p * NH + head];
    __half a1h = att[(size_t)(p + 8) * NH + head];
    int sn0 = srcc[p];
    int sn1 = srcc[p + 8];
    R20 r0 = ldrow20(Hin + ((size_t)sn0 * NH + head) * 20);
    R20 r1 = ldrow20(Hin + ((size_t)sn1 * NH + head) * 20);
    __half2 a0 = __half2half2(a0h);
    __half2 a1 = __half2half2(a1h);
#pragma unroll
    for (int q = 0; q < 10; q++) {
      agg[q] = __hfma2(a0, r0.h[q], agg[q]);
      agg[q] = __hfma2(a1, r1.h[q], agg[q]);
    }
    p += 16;
  }
  if (p < end) {
    __half a0h = att[(size_t)p * NH + head];
    int sn0 = srcc[p];
    R20 r0 = ldrow20(Hin + ((size_t)sn0 * NH + head) * 20);
    __half2 a0 = __half2half2(a0h);
#pragma unroll
    for (int q = 0; q < 10; q++) agg[q] = __hfma2(a0, r0.h[q], agg[q]);
  }
#pragma unroll
  for (int q = 0; q < 10; q++) SLOTRED_H2(agg[q]);

  // all lanes: combine, head-mean, ELU -> full h vector in f32
  __half2 s2 = __float2half2_rn(invden[g] * (1.0f - ALPHA));
  __half2 al = __float2half2_rn(ALPHA);
  float o[C];
#pragma unroll
  for (int q = 0; q < 10; q++) {
    __half2 m = __hfma2(s2, agg[q], __hmul2(al, h0.h[q]));
    m = __hadd2(m, H2SWZ(m, 0x041F));   // + head^1
    m = __hadd2(m, H2SWZ(m, 0x081F));   // + head^2
    float2 f = __half22float2(m);
    float v0 = f.x * 0.25f, v1 = f.y * 0.25f;
    o[2 * q]     = v0 > 0.f ? v0 : __expf(v0) - 1.f;
    o[2 * q + 1] = v1 > 0.f ? v1 : __expf(v1) - 1.f;
  }

  // distributed projection: slot s handles d = s, s+8, s+16 (<20)
  float esp = 0.f, edp = 0.f;
#pragma unroll
  for (int j = 0; j < 3; j++) {
    int d = eslot + j * 8;
    if (d < C) {
      const float* wrow = &sWt[(head * C + d) * WSTRIDE];
      float zv = 0.f;
#pragma unroll
      for (int c = 0; c < C; c++) zv += o[c] * wrow[c];
      esp += zv * sa[head * C + d];
      edp += zv * sd[head * C + d];
      zb[((size_t)n * NH + head) * 20 + d] = __float2half_rn(zv);
    }
  }
  esp += FSWZ(esp, 0x101F);
  esp += FSWZ(esp, 0x201F);
  esp += FSWZ(esp, 0x401F);
  edp += FSWZ(edp, 0x101F);
  edp += FSWZ(edp, 0x201F);
  edp += FSWZ(edp, 0x401F);
  if (eslot == 0) {
    es[g] = esp;
    ed[g] = edp;
  }
}

#define RSPAN 16
__global__ __launch_bounds__(256) void k_hop_last_final(
    const int* __restrict__ offs, const int* __restrict__ deg,
    const int* __restrict__ srcc,
    const __half* __restrict__ att, const float* __restrict__ invden,
    const __half* __restrict__ Hin, const __half* __restrict__ Zt,
    const int* __restrict__ gids, const float* __restrict__ wsW,
    const float* __restrict__ wsb, float* __restrict__ out)
{
  __shared__ float sacc[RSPAN * C];
  __shared__ int sgmin;
  const int t = threadIdx.x;
  const int head = t & 3;
  const int eslot = (t >> 2) & 7;
  const int n = blockIdx.x * 8 + (t >> 5);
  const int g = n * NH + head;
  const int beg = offs[n], end = beg + deg[n];
  for (int i = t; i < RSPAN * C; i += 256) sacc[i] = 0.f;
  if (t == 0) sgmin = gids[blockIdx.x * 8];
  __syncthreads();
  R20 h0 = ldrow20(Zt + ((size_t)n * NH + head) * 20);     // hoisted self-row
  __half2 agg[10];
#pragma unroll
  for (int q = 0; q < 10; q++) agg[q] = __floats2half2_rn(0.f, 0.f);
  int p = beg + eslot;
  while (p + 8 < end) {
    __half a0h = att[(size_t)p * NH + head];
    __half a1h = att[(size_t)(p + 8) * NH + head];
    int sn0 = srcc[p];
    int sn1 = srcc[p + 8];
    R20 r0 = ldrow20(Hin + ((size_t)sn0 * NH + head) * 20);
    R20 r1 = ldrow20(Hin + ((size_t)sn1 * NH + head) * 20);
    __half2 a0 = __half2half2(a0h);
    __half2 a1 = __half2half2(a1h);
#pragma unroll
    for (int q = 0; q < 10; q++) {
      agg[q] = __hfma2(a0, r0.h[q], agg[q]);
      agg[q] = __hfma2(a1, r1.h[q], agg[q]);
    }
    p += 16;
  }
  if (p < end) {
    __half a0h = att[(size_t)p * NH + head];
    int sn0 = srcc[p];
    R20 r0 = ldrow20(Hin + ((size_t)sn0 * NH + head) * 20);
    __half2 a0 = __half2half2(a0h);
#pragma unroll
    for (int q = 0; q < 10; q++) agg[q] = __hfma2(a0, r0.h[q], agg[q]);
  }
#pragma unroll
  for (int q = 0; q < 10; q++) SLOTRED_H2(agg[q]);
  if (eslot == 0) {
    __half2 s2 = __float2half2_rn(invden[g] * (1.0f - ALPHA));
    __half2 al = __float2half2_rn(ALPHA);
    float o[C];
#pragma unroll
    for (int q = 0; q < 10; q++) {
      __half2 m = __hfma2(s2, agg[q], __hmul2(al, h0.h[q]));
      m = __hadd2(m, H2SWZ(m, 0x041F));
      m = __hadd2(m, H2SWZ(m, 0x081F));
      float2 f = __half22float2(m);
      o[2 * q]     = f.x * 0.25f;
      o[2 * q + 1] = f.y * 0.25f;
    }
    // distributed gate dot: partial on own 5 channels, reduce over heads
    float dotp = 0.f;
#pragma unroll
    for (int j = 0; j < 5; j++) {
      int c = head * 5 + j;
      dotp += o[c] * wsW[c];
    }
    dotp += FSWZ(dotp, 0x041F);
    dotp += FSWZ(dotp, 0x081F);
    const float gate = 1.f / (1.f + __expf(-(dotp + wsb[0])));
    const int b = gids[n];
    const int lb = b - sgmin;
    if (lb < RSPAN) {
#pragma unroll
      for (int j = 0; j < 5; j++) {
        int c = head * 5 + j;
        atomicAdd(&sacc[lb * C + c], o[c] * gate);
      }
    } else {
#pragma unroll
      for (int j = 0; j < 5; j++) {
        int c = head * 5 + j;
        atomicAdd(&out[(size_t)b * C + c], o[c] * gate);
      }
    }
  }
  __syncthreads();
  for (int i = t; i < RSPAN * C; i += 256) {
    float v = sacc[i];
    if (v != 0.f) atomicAdd(&out[(size_t)(sgmin + i / C) * C + (i - (i / C) * C)], v);
  }
}

// ---------------------------------------------------------------------------
extern "C" void kernel_launch(void* const* d_in, const int* in_sizes, int n_in,
                              void* d_out, int out_size, void* d_ws, size_t ws_size,
                              hipStream_t stream)
{
  const int*   node_ids = (const int*)  d_in[0];
  const int*   edge_src = (const int*)  d_in[1];
  const int*   edge_dst = (const int*)  d_in[2];
  const int*   graph_ids= (const int*)  d_in[3];
  const float* emb      = (const float*)d_in[4];
  const float* W1       = (const float*)d_in[5];
  const float* b1       = (const float*)d_in[6];
  const float* W2       = (const float*)d_in[7];
  const float* b2       = (const float*)d_in[8];
  const float* gat_W    = (const float*)d_in[9];
  const float* gat_asrc = (const float*)d_in[10];
  const float* gat_adst = (const float*)d_in[11];
  const float* ws_W     = (const float*)d_in[12];
  const float* ws_b     = (const float*)d_in[13];
  float* out = (float*)d_out;

  // ---- workspace (~66 MB). X region time-shared: gbuf -> att ----
  float* esf    = (float*)d_ws;                      // VPAD*NH
  float* edf    = esf   + (size_t)VPAD * NH;
  float* es     = edf   + (size_t)VPAD * NH;         // N*NH
  float* ed     = es    + (size_t)NNODE * NH;
  float* invden = ed    + (size_t)NNODE * NH;
  float* bb     = invden+ (size_t)NNODE * NH;        // 96
  float* coef   = bb + 96;                           // 96*20
  int*   offs   = (int*)(coef + 96 * C);             // N
  int*   deg    = offs + NNODE;                      // N
  int*   gcur   = deg + NNODE;                       // 300
  int*   srcc   = gcur + NBKT;                       // NSLOT
  int*   srcv   = srcc + NSLOT;                      // NSLOT
  uintptr_t a16 = ((uintptr_t)(srcv + NSLOT) + 15) & ~(uintptr_t)15;
  __half* zfull = (__half*)a16;                      // VPAD*NH*20
  __half* zb    = zfull + (size_t)VPAD * NH * 20;    // N*NH*20
  __half* bufA  = zb    + (size_t)NNODE * NH * 20;
  __half* bufB  = bufA  + (size_t)NNODE * NH * 20;
  ushort* W1t   = (ushort*)(bufB + (size_t)NNODE * NH * 20);  // 40*512*8
  ushort* Wcpt  = W1t + (size_t)40 * 512 * 8;        // 64*96*8
  uintptr_t x16 = ((uintptr_t)(Wcpt + 64 * 96 * 8) + 15) & ~(uintptr_t)15;
  int*    gbuf  = (int*)x16;                         // X: NSLOT ints
  __half* att   = (__half*)x16;                      // X: NH*NSLOT halves

  hipMemsetAsync(out, 0, (size_t)NB * C * sizeof(float), stream);
  hipMemsetAsync(gcur, 0, NBKT * sizeof(int), stream);

  // prep
  k_cvt_w1<<<(40 * 512 * 8) / 256, 256, 0, stream>>>(W1, W1t);
  k_prep_coef<<<1, 128, 0, stream>>>(gat_W, gat_asrc, gat_adst, b2, coef, bb);
  k_prep_wcp<<<(64 * 96 * 8) / 256, 256, 0, stream>>>(W2, coef, Wcpt);

  // CSR build (gapped buckets; X: gbuf)
  k_bkt_scatter<<<NEBLK, 256, 0, stream>>>(edge_src, edge_dst, gcur, gbuf);
  k_csr_build<<<NBKT, 256, 0, stream>>>(gcur, gbuf, node_ids,
                                        offs, deg, srcc, srcv);

  // MLP + folded layer-0 GAT projection (reads f32 emb directly)
  k_mlp_mfma<<<VPAD / BM, 512, 0, stream>>>(emb, W1t, b1, Wcpt, bb,
                                            zfull, esf, edf);

  const int HB = NNODE / 8;   // 9600 blocks for hop kernels (X: att)
  // layer 0 (vocab-space z); last hop fused with layer-1 projection
  k_hop_first<<<HB, 256, 0, stream>>>(offs, deg, srcv, esf, edf, node_ids,
                                      zfull, att, invden, bufA);
  k_hop_mid<<<HB, 256, 0, stream>>>(offs, deg, srcc, att, invden, bufA, zfull,
                                    node_ids, bufB);
  k_hop_last_proj<<<HB, 256, 0, stream>>>(offs, deg, srcc, att, invden, bufB,
                                          zfull, node_ids,
                                          gat_W + (size_t)NH * C * C,
                                          gat_asrc + NH * C, gat_adst + NH * C,
                                          zb, es, ed);
  // layer 1
  k_hop_first<<<HB, 256, 0, stream>>>(offs, deg, srcc, es, ed,
                                      (const int*)nullptr, zb, att, invden,
                                      bufA);
  k_hop_mid<<<HB, 256, 0, stream>>>(offs, deg, srcc, att, invden, bufA, zb,
                                    (const int*)nullptr, bufB);
  k_hop_last_final<<<HB, 256, 0, stream>>>(offs, deg, srcc, att, invden, bufB,
                                           zb, graph_ids, ws_W, ws_b, out);
}

// Round 19
// 398.200 us; speedup vs baseline: 1.0545x; 1.0229x over previous
//
#include <hip/hip_runtime.h>
#include <hip/hip_bf16.h>
#include <hip/hip_fp16.h>
#include <math.h>

#define VOCAB 50000
#define FEAT 300
#define KPAD 320
#define HID 512
#define C 20
#define NL 2
#define NH 4
#define KHOP 3
#define ALPHA 0.1f
#define NNODE 76800
#define NEDGE 1250000
#define NB 512
#define SLOPE 0.2f

#define NBKT 300
#define BKTCAP 5120
#define NSLOT (NBKT * BKTCAP)
#define EPB 5120
#define NEBLK ((NEDGE + EPB - 1) / EPB)   // 245

#define BM 32
#define VPAD 50048          // 1564 * 32
#define SX_STRIDE 520
#define WSTRIDE 21          // padded LDS stride for transposed W (bank spread)

typedef float f32x4 __attribute__((ext_vector_type(4)));
typedef short bf16x8 __attribute__((ext_vector_type(8)));

__device__ inline unsigned short f2b(float x) {
  __hip_bfloat16 h = __float2bfloat16(x);
  return *reinterpret_cast<unsigned short*>(&h);
}

// 40B row of fp16 (exactly 20 halves, 8B-aligned)
union R20 {
  struct { uint4 a, b; uint2 c; } v;
  __half2 h[10];
};
__device__ inline R20 ldrow20(const __half* p) {
  R20 r;
  r.v.a = *(const uint4*)p;
  r.v.b = *(const uint4*)(p + 8);
  r.v.c = *(const uint2*)(p + 16);
  return r;
}
__device__ inline void strow20(__half* p, const R20& r) {
  *(uint4*)p = r.v.a;
  *(uint4*)(p + 8) = r.v.b;
  *(uint2*)(p + 16) = r.v.c;
}

// single-instruction cross-lane xor swizzles (bitmode: (xor<<10)|0x1F)
#define H2SWZ(v, pat) ({ union { __half2 h; int i; } _u; _u.h = (v);          \
                         _u.i = __builtin_amdgcn_ds_swizzle(_u.i, (pat));     \
                         _u.h; })
#define FSWZ(x, pat) __int_as_float(                                          \
    __builtin_amdgcn_ds_swizzle(__float_as_int(x), (pat)))
// slot reduce: lanes differ in bits 2..4 -> xor 4, 8, 16
#define SLOTRED_H2(v) do {                                                    \
    v = __hadd2(v, H2SWZ(v, 0x101F));                                         \
    v = __hadd2(v, H2SWZ(v, 0x201F));                                         \
    v = __hadd2(v, H2SWZ(v, 0x401F)); } while (0)

// ---------------------------------------------------------------------------
// prep kernels
// ---------------------------------------------------------------------------
__global__ void k_cvt_w1(const float* __restrict__ W1, ushort* __restrict__ W1t)
{
  int idx = blockIdx.x * 256 + threadIdx.x;   // 40*512*8 = 163840
  int kc = idx >> 12;
  int rem = idx & 4095;
  int col = rem >> 3;
  int j = rem & 7;
  int k = kc * 8 + j;
  W1t[idx] = (k < FEAT) ? f2b(W1[(size_t)k * HID + col]) : (ushort)0;
}

__global__ void k_prep_coef(const float* __restrict__ gatW0,
                            const float* __restrict__ as0,
                            const float* __restrict__ ad0,
                            const float* __restrict__ b2,
                            float* __restrict__ coef, float* __restrict__ bb)
{
  int col = threadIdx.x;
  if (col >= 96) return;
  float cf[C];
  if (col < 80) {
    int hd = col / C, d = col - hd * C;
#pragma unroll
    for (int j = 0; j < C; j++) cf[j] = gatW0[(hd * C + j) * C + d];
  } else if (col < 88) {
    int hd = col - 80;
#pragma unroll
    for (int j = 0; j < C; j++) {
      float s = 0.f;
#pragma unroll
      for (int d = 0; d < C; d++) s += gatW0[(hd * C + j) * C + d] * as0[hd * C + d];
      cf[j] = s;
    }
  } else {
    int hd = col - 88;
#pragma unroll
    for (int j = 0; j < C; j++) {
      float s = 0.f;
#pragma unroll
      for (int d = 0; d < C; d++) s += gatW0[(hd * C + j) * C + d] * ad0[hd * C + d];
      cf[j] = s;
    }
  }
  float bbv = 0.f;
#pragma unroll
  for (int j = 0; j < C; j++) { coef[col * C + j] = cf[j]; bbv += b2[j] * cf[j]; }
  bb[col] = bbv;
}

__global__ void k_prep_wcp(const float* __restrict__ W2,
                           const float* __restrict__ coef,
                           ushort* __restrict__ Wcpt)
{
  int idx = blockIdx.x * 256 + threadIdx.x;   // 64*96*8 = 49152
  int kc = idx / 768;
  int rem = idx - kc * 768;
  int col = rem >> 3;
  int j = rem & 7;
  int k = kc * 8 + j;
  float s = 0.f;
#pragma unroll
  for (int jj = 0; jj < C; jj++) s += W2[(size_t)k * C + jj] * coef[col * C + jj];
  Wcpt[idx] = f2b(s);
}

// ---------------------------------------------------------------------------
// K1: per vocab row: x = relu(emb@W1+b1); [z(80) es(4) ed(4)] = x@Wc + bb
// z written in packed-20 layout: zfull[(v*4+h)*20 + c]
// ---------------------------------------------------------------------------
__global__ __launch_bounds__(512, 6) void k_mlp_mfma(
    const float* __restrict__ emb, const ushort* __restrict__ W1t,
    const float* __restrict__ b1, const ushort* __restrict__ Wcpt,
    const float* __restrict__ bb, __half* __restrict__ zfull,
    float* __restrict__ esf, float* __restrict__ edf)
{
  __shared__ ushort smem[16640];   // 33.3KB: sA [40][32][8] (20KB) / sX [32][520]
  ushort* sA = smem;
  ushort* sX = smem;

  const int t = threadIdx.x;
  const int lane = t & 63;
  const int w = t >> 6;
  const int v0 = blockIdx.x * BM;
  const int l15 = lane & 15;
  const int l4 = lane >> 4;
  const int cb = w * 64;             // wave col base (64 distinct cols)

  // stage A: 1280 16B chunks, [kc][row][8], with on-the-fly f32->bf16
#pragma unroll
  for (int j = 0; j < 3; j++) {
    int chunk = j * 512 + t;
    if (chunk < 1280) {
      int row = chunk & 31;
      int kc = chunk >> 5;
      int vr = v0 + row;
      if (vr >= VOCAB) vr = VOCAB - 1;
      int k0 = kc * 8;
      const float* p = emb + (size_t)vr * FEAT + k0;
      ushort u[8];
      if (k0 + 8 <= FEAT) {
        float4 x = *(const float4*)p;
        float4 y = *(const float4*)(p + 4);
        u[0] = f2b(x.x); u[1] = f2b(x.y); u[2] = f2b(x.z); u[3] = f2b(x.w);
        u[4] = f2b(y.x); u[5] = f2b(y.y); u[6] = f2b(y.z); u[7] = f2b(y.w);
      } else {
#pragma unroll
        for (int q = 0; q < 8; q++)
          u[q] = (k0 + q < FEAT) ? f2b(p[q]) : (ushort)0;
      }
      *(uint4*)(sA + (size_t)chunk * 8) = *(const uint4*)u;
    }
  }
  __syncthreads();

  f32x4 acc[2][4];
#pragma unroll
  for (int rt = 0; rt < 2; rt++)
#pragma unroll
    for (int ct = 0; ct < 4; ct++) acc[rt][ct] = (f32x4)0.f;

  for (int ks = 0; ks < 10; ks++) {
    const int kcb = ks * 4 + l4;
    bf16x8 a0 = *(const bf16x8*)(sA + ((size_t)kcb * 32 + l15) * 8);
    bf16x8 a1 = *(const bf16x8*)(sA + ((size_t)kcb * 32 + 16 + l15) * 8);
    const ushort* wb = W1t + ((size_t)kcb * 512 + cb + l15) * 8;
    bf16x8 bf[4];
#pragma unroll
    for (int ct = 0; ct < 4; ct++) bf[ct] = *(const bf16x8*)(wb + ct * 128);
#pragma unroll
    for (int ct = 0; ct < 4; ct++) {
      acc[0][ct] = __builtin_amdgcn_mfma_f32_16x16x32_bf16(a0, bf[ct], acc[0][ct], 0, 0, 0);
      acc[1][ct] = __builtin_amdgcn_mfma_f32_16x16x32_bf16(a1, bf[ct], acc[1][ct], 0, 0, 0);
    }
  }
  __syncthreads();   // all sA reads done

  // x = relu(acc + b1) -> sX bf16 [32][520]
#pragma unroll
  for (int rt = 0; rt < 2; rt++)
#pragma unroll
    for (int ct = 0; ct < 4; ct++) {
      int col = cb + ct * 16 + l15;
      float bias = b1[col];
#pragma unroll
      for (int r4 = 0; r4 < 4; r4++) {
        int row = rt * 16 + l4 * 4 + r4;
        float x = fmaxf(acc[rt][ct][r4] + bias, 0.f);
        sX[(size_t)row * SX_STRIDE + col] = f2b(x);
      }
    }
  __syncthreads();

  // phase2: 12 tiles (2 rt x 6 ct); wave w does tile w, and 8+w if w<4
  const int ntile = (w < 4) ? 2 : 1;
  for (int i = 0; i < ntile; i++) {
    const int tt = (i == 0) ? w : 8 + w;
    const int rt = tt & 1, ct = tt >> 1;
    const ushort* xb = sX + (size_t)(rt * 16 + l15) * SX_STRIDE + l4 * 8;
    const ushort* wbp = Wcpt + ((size_t)l4 * 96 + ct * 16 + l15) * 8;
    bf16x8 bv[16];
#pragma unroll
    for (int ks = 0; ks < 16; ks++)
      bv[ks] = *(const bf16x8*)(wbp + (size_t)ks * 3072);   // kc += 4
    f32x4 a2 = (f32x4)0.f;
#pragma unroll
    for (int ks = 0; ks < 16; ks++) {
      bf16x8 av = *(const bf16x8*)(xb + ks * 32);
      a2 = __builtin_amdgcn_mfma_f32_16x16x32_bf16(av, bv[ks], a2, 0, 0, 0);
    }
    const int col = ct * 16 + l15;
    const float bias = bb[col];
#pragma unroll
    for (int r = 0; r < 4; r++) {
      const int vrow = v0 + rt * 16 + l4 * 4 + r;
      if (vrow >= VOCAB) continue;
      float val = a2[r] + bias;
      if (col < 80) {
        int hd = col / C, c = col - hd * C;
        zfull[((size_t)vrow * NH + hd) * 20 + c] = __float2half_rn(val);
      } else if (col < 88) {
        esf[(size_t)vrow * NH + (col - 80)] = val;
      } else {
        edf[(size_t)vrow * NH + (col - 88)] = val;
      }
    }
  }
}

// ---------------------------------------------------------------------------
// CSR build: gapped buckets (fixed capacity)
// ---------------------------------------------------------------------------
__global__ __launch_bounds__(256) void k_bkt_scatter(
    const int* __restrict__ src, const int* __restrict__ dst,
    int* __restrict__ gcur, int* __restrict__ gbuf)
{
  __shared__ int hist[NBKT];
  __shared__ int lcur[NBKT];
  const int t = threadIdx.x;
  for (int i = t; i < NBKT; i += 256) hist[i] = 0;
  __syncthreads();
  const int base = blockIdx.x * EPB;
#pragma unroll
  for (int j = 0; j < 20; j++) {
    int e = base + j * 256 + t;
    if (e < NEDGE) atomicAdd(&hist[dst[e] >> 8], 1);
  }
  __syncthreads();
  for (int i = t; i < NBKT; i += 256) {
    int v = hist[i];
    lcur[i] = v ? atomicAdd(&gcur[i], v) : 0;
  }
  __syncthreads();
#pragma unroll
  for (int j = 0; j < 20; j++) {
    int e = base + j * 256 + t;
    if (e < NEDGE) {
      int d = dst[e];
      int b = d >> 8;
      int idx = atomicAdd(&lcur[b], 1);
      if (idx < BKTCAP)
        gbuf[(size_t)b * BKTCAP + idx] = (src[e] << 8) | (d & 255);
    }
  }
}

__global__ __launch_bounds__(256) void k_csr_build(
    const int* __restrict__ gcur, const int* __restrict__ gbuf,
    const int* __restrict__ node_ids, int* __restrict__ offs,
    int* __restrict__ deg, int* __restrict__ srcc, int* __restrict__ srcv)
{
  __shared__ int shist[256];
  __shared__ int lcur[256];
  __shared__ int wsum[4];
  const int b = blockIdx.x;
  const int t = threadIdx.x;
  const int base = b * BKTCAP;
  int nb = gcur[b];
  if (nb > BKTCAP) nb = BKTCAP;
  shist[t] = 0;
  __syncthreads();
  for (int i = t; i < nb; i += 256)
    atomicAdd(&shist[gbuf[base + i] & 255], 1);
  __syncthreads();
  int v = shist[t];
  int x = v;
#pragma unroll
  for (int off = 1; off < 64; off <<= 1) {
    int y = __shfl_up(x, off, 64);
    if ((t & 63) >= off) x += y;
  }
  if ((t & 63) == 63) wsum[t >> 6] = x;
  __syncthreads();
  int waveoff = 0;
#pragma unroll
  for (int w = 0; w < 4; w++) waveoff += (w < (t >> 6)) ? wsum[w] : 0;
  int pre = base + waveoff + x - v;
  offs[b * 256 + t] = pre;
  deg[b * 256 + t] = v;
  lcur[t] = pre;
  __syncthreads();
  for (int i = t; i < nb; i += 256) {
    int p = gbuf[base + i];
    int slot = atomicAdd(&lcur[p & 255], 1);
    int s = p >> 8;
    srcc[slot] = s;
    srcv[slot] = node_ids[s];
  }
}

// ---------------------------------------------------------------------------
// Hop kernels: 32 lanes/node (4 heads x 8 edge-slots), 8 nodes/block.
// Packed 40B rows; 2-way unrolled gathers; swizzle reduces; hoisted h0.
// ---------------------------------------------------------------------------
__global__ __launch_bounds__(256) void k_hop_first(
    const int* __restrict__ offs, const int* __restrict__ deg,
    const int* __restrict__ sidx,
    const float* __restrict__ esT, const float* __restrict__ edT,
    const int* __restrict__ ids, const __half* __restrict__ Zt,
    __half* __restrict__ att, float* __restrict__ invden,
    __half* __restrict__ Hout)
{
  const int t = threadIdx.x;
  const int head = t & 3;
  const int eslot = (t >> 2) & 7;
  const int n = blockIdx.x * 8 + (t >> 5);
  const int g = n * NH + head;
  const int idn = ids ? ids[n] : n;
  const int beg = offs[n], end = beg + deg[n];
  const float edv = edT[(size_t)idn * NH + head];
  R20 h0 = ldrow20(Zt + ((size_t)idn * NH + head) * 20);   // hoisted self-row
  __half2 agg[10];
#pragma unroll
  for (int q = 0; q < 10; q++) agg[q] = __floats2half2_rn(0.f, 0.f);
  float den = 0.f;
  int p = beg + eslot;
  while (p + 8 < end) {
    int sv0 = sidx[p];
    int sv1 = sidx[p + 8];
    float es0 = esT[(size_t)sv0 * NH + head];
    float es1 = esT[(size_t)sv1 * NH + head];
    R20 r0 = ldrow20(Zt + ((size_t)sv0 * NH + head) * 20);
    R20 r1 = ldrow20(Zt + ((size_t)sv1 * NH + head) * 20);
    float e0 = es0 + edv; e0 = e0 > 0.f ? e0 : SLOPE * e0;
    float e1 = es1 + edv; e1 = e1 > 0.f ? e1 : SLOPE * e1;
    float ex0 = __expf(e0), ex1 = __expf(e1);
    att[(size_t)p * NH + head] = __float2half_rn(ex0);
    att[(size_t)(p + 8) * NH + head] = __float2half_rn(ex1);
    den += ex0 + ex1;
    __half2 a0 = __float2half2_rn(ex0);
    __half2 a1 = __float2half2_rn(ex1);
#pragma unroll
    for (int q = 0; q < 10; q++) {
      agg[q] = __hfma2(a0, r0.h[q], agg[q]);
      agg[q] = __hfma2(a1, r1.h[q], agg[q]);
    }
    p += 16;
  }
  if (p < end) {
    int sv0 = sidx[p];
    float es0 = esT[(size_t)sv0 * NH + head];
    R20 r0 = ldrow20(Zt + ((size_t)sv0 * NH + head) * 20);
    float e0 = es0 + edv; e0 = e0 > 0.f ? e0 : SLOPE * e0;
    float ex0 = __expf(e0);
    att[(size_t)p * NH + head] = __float2half_rn(ex0);
    den += ex0;
    __half2 a0 = __float2half2_rn(ex0);
#pragma unroll
    for (int q = 0; q < 10; q++) agg[q] = __hfma2(a0, r0.h[q], agg[q]);
  }
#pragma unroll
  for (int q = 0; q < 10; q++) SLOTRED_H2(agg[q]);
  den += FSWZ(den, 0x101F);
  den += FSWZ(den, 0x201F);
  den += FSWZ(den, 0x401F);
  if (eslot == 0) {
    float inv = 1.f / (den + 1e-9f);
    invden[g] = inv;
    __half2 s2 = __float2half2_rn(inv * (1.0f - ALPHA));
    __half2 al = __float2half2_rn(ALPHA);
    R20 o;
#pragma unroll
    for (int q = 0; q < 10; q++)
      o.h[q] = __hfma2(s2, agg[q], __hmul2(al, h0.h[q]));
    strow20(Hout + (size_t)g * 20, o);
  }
}

__global__ __launch_bounds__(256) void k_hop_mid(
    const int* __restrict__ offs, const int* __restrict__ deg,
    const int* __restrict__ srcc,
    const __half* __restrict__ att, const float* __restrict__ invden,
    const __half* __restrict__ Hin, const __half* __restrict__ Zt,
    const int* __restrict__ ids, __half* __restrict__ Hout)
{
  const int t = threadIdx.x;
  const int head = t & 3;
  const int eslot = (t >> 2) & 7;
  const int n = blockIdx.x * 8 + (t >> 5);
  const int g = n * NH + head;
  const int idn = ids ? ids[n] : n;
  const int beg = offs[n], end = beg + deg[n];
  R20 h0 = ldrow20(Zt + ((size_t)idn * NH + head) * 20);   // hoisted self-row
  __half2 agg[10];
#pragma unroll
  for (int q = 0; q < 10; q++) agg[q] = __floats2half2_rn(0.f, 0.f);
  int p = beg + eslot;
  while (p + 8 < end) {
    __half a0h = att[(size_t)p * NH + head];
    __half a1h = att[(size_t)(p + 8) * NH + head];
    int sn0 = srcc[p];
    int sn1 = srcc[p + 8];
    R20 r0 = ldrow20(Hin + ((size_t)sn0 * NH + head) * 20);
    R20 r1 = ldrow20(Hin + ((size_t)sn1 * NH + head) * 20);
    __half2 a0 = __half2half2(a0h);
    __half2 a1 = __half2half2(a1h);
#pragma unroll
    for (int q = 0; q < 10; q++) {
      agg[q] = __hfma2(a0, r0.h[q], agg[q]);
      agg[q] = __hfma2(a1, r1.h[q], agg[q]);
    }
    p += 16;
  }
  if (p < end) {
    __half a0h = att[(size_t)p * NH + head];
    int sn0 = srcc[p];
    R20 r0 = ldrow20(Hin + ((size_t)sn0 * NH + head) * 20);
    __half2 a0 = __half2half2(a0h);
#pragma unroll
    for (int q = 0; q < 10; q++) agg[q] = __hfma2(a0, r0.h[q], agg[q]);
  }
#pragma unroll
  for (int q = 0; q < 10; q++) SLOTRED_H2(agg[q]);
  if (eslot == 0) {
    __half2 s2 = __float2half2_rn(invden[g] * (1.0f - ALPHA));
    __half2 al = __float2half2_rn(ALPHA);
    R20 o;
#pragma unroll
    for (int q = 0; q < 10; q++)
      o.h[q] = __hfma2(s2, agg[q], __hmul2(al, h0.h[q]));
    strow20(Hout + (size_t)g * 20, o);
  }
}

// ---------------------------------------------------------------------------
// Layer-0 last hop FUSED with layer-1 GAT projection.
// W1 transposed+padded in LDS: sWt[h][d][21] -> stride-1 c loop, bank-spread.
// ---------------------------------------------------------------------------
__global__ __launch_bounds__(256) void k_hop_last_proj(
    const int* __restrict__ offs, const int* __restrict__ deg,
    const int* __restrict__ srcc,
    const __half* __restrict__ att, const float* __restrict__ invden,
    const __half* __restrict__ Hin, const __half* __restrict__ Zt,
    const int* __restrict__ ids,
    const float* __restrict__ gatW1, const float* __restrict__ as1,
    const float* __restrict__ ad1,
    __half* __restrict__ zb, float* __restrict__ es, float* __restrict__ ed)
{
  __shared__ float sWt[NH * C * WSTRIDE];   // [h][d][21]
  __shared__ float sa[NH * C], sd[NH * C];
  const int t = threadIdx.x;
  for (int i = t; i < NH * C * C; i += 256) {
    int h = i / (C * C);
    int r = i - h * C * C;
    int c = r / C;
    int d = r - c * C;
    sWt[(h * C + d) * WSTRIDE + c] = gatW1[i];
  }
  if (t < NH * C) { sa[t] = as1[t]; sd[t] = ad1[t]; }
  __syncthreads();

  const int head = t & 3;
  const int eslot = (t >> 2) & 7;
  const int n = blockIdx.x * 8 + (t >> 5);
  const int g = n * NH + head;
  const int idn = ids ? ids[n] : n;
  const int beg = offs[n], end = beg + deg[n];
  R20 h0 = ldrow20(Zt + ((size_t)idn * NH + head) * 20);   // hoisted self-row
  __half2 agg[10];
#pragma unroll
  for (int q = 0; q < 10; q++) agg[q] = __floats2half2_rn(0.f, 0.f);
  int p = beg + eslot;
  while (p + 8 < end) {
    __half a0h = att[(size_t)p * NH + head];
    __half a1h = att[(size_t)(p + 8) * NH + head];
    int sn0 = srcc[p];
    int sn1 = srcc[p + 8];
    R20 r0 = ldrow20(Hin + ((size_t)sn0 * NH + head) * 20);
    R20 r1 = ldrow20(Hin + ((size_t)sn1 * NH + head) * 20);
    __half2 a0 = __half2half2(a0h);
    __half2 a1 = __half2half2(a1h);
#pragma unroll
    for (int q = 0; q < 10; q++) {
      agg[q] = __hfma2(a0, r0.h[q], agg[q]);
      agg[q] = __hfma2(a1, r1.h[q], agg[q]);
    }
    p += 16;
  }
  if (p < end) {
    __half a0h = att[(size_t)p * NH + head];
    int sn0 = srcc[p];
    R20 r0 = ldrow20(Hin + ((size_t)sn0 * NH + head) * 20);
    __half2 a0 = __half2half2(a0h);
#pragma unroll
    for (int q = 0; q < 10; q++) agg[q] = __hfma2(a0, r0.h[q], agg[q]);
  }
#pragma unroll
  for (int q = 0; q < 10; q++) SLOTRED_H2(agg[q]);

  // all lanes: combine, head-mean, ELU -> full h vector in f32
  __half2 s2 = __float2half2_rn(invden[g] * (1.0f - ALPHA));
  __half2 al = __float2half2_rn(ALPHA);
  float o[C];
#pragma unroll
  for (int q = 0; q < 10; q++) {
    __half2 m = __hfma2(s2, agg[q], __hmul2(al, h0.h[q]));
    m = __hadd2(m, H2SWZ(m, 0x041F));   // + head^1
    m = __hadd2(m, H2SWZ(m, 0x081F));   // + head^2
    float2 f = __half22float2(m);
    float v0 = f.x * 0.25f, v1 = f.y * 0.25f;
    o[2 * q]     = v0 > 0.f ? v0 : __expf(v0) - 1.f;
    o[2 * q + 1] = v1 > 0.f ? v1 : __expf(v1) - 1.f;
  }

  // distributed projection: slot s handles d = s, s+8, s+16 (<20)
  float esp = 0.f, edp = 0.f;
#pragma unroll
  for (int j = 0; j < 3; j++) {
    int d = eslot + j * 8;
    if (d < C) {
      const float* wrow = &sWt[(head * C + d) * WSTRIDE];
      float zv = 0.f;
#pragma unroll
      for (int c = 0; c < C; c++) zv += o[c] * wrow[c];
      esp += zv * sa[head * C + d];
      edp += zv * sd[head * C + d];
      zb[((size_t)n * NH + head) * 20 + d] = __float2half_rn(zv);
    }
  }
  esp += FSWZ(esp, 0x101F);
  esp += FSWZ(esp, 0x201F);
  esp += FSWZ(esp, 0x401F);
  edp += FSWZ(edp, 0x101F);
  edp += FSWZ(edp, 0x201F);
  edp += FSWZ(edp, 0x401F);
  if (eslot == 0) {
    es[g] = esp;
    ed[g] = edp;
  }
}

#define RSPAN 16
__global__ __launch_bounds__(256) void k_hop_last_final(
    const int* __restrict__ offs, const int* __restrict__ deg,
    const int* __restrict__ srcc,
    const __half* __restrict__ att, const float* __restrict__ invden,
    const __half* __restrict__ Hin, const __half* __restrict__ Zt,
    const int* __restrict__ gids, const float* __restrict__ wsW,
    const float* __restrict__ wsb, float* __restrict__ out)
{
  __shared__ float sacc[RSPAN * C];
  __shared__ int sgmin;
  const int t = threadIdx.x;
  const int head = t & 3;
  const int eslot = (t >> 2) & 7;
  const int n = blockIdx.x * 8 + (t >> 5);
  const int g = n * NH + head;
  const int beg = offs[n], end = beg + deg[n];
  for (int i = t; i < RSPAN * C; i += 256) sacc[i] = 0.f;
  if (t == 0) sgmin = gids[blockIdx.x * 8];
  __syncthreads();
  R20 h0 = ldrow20(Zt + ((size_t)n * NH + head) * 20);     // hoisted self-row
  __half2 agg[10];
#pragma unroll
  for (int q = 0; q < 10; q++) agg[q] = __floats2half2_rn(0.f, 0.f);
  int p = beg + eslot;
  while (p + 8 < end) {
    __half a0h = att[(size_t)p * NH + head];
    __half a1h = att[(size_t)(p + 8) * NH + head];
    int sn0 = srcc[p];
    int sn1 = srcc[p + 8];
    R20 r0 = ldrow20(Hin + ((size_t)sn0 * NH + head) * 20);
    R20 r1 = ldrow20(Hin + ((size_t)sn1 * NH + head) * 20);
    __half2 a0 = __half2half2(a0h);
    __half2 a1 = __half2half2(a1h);
#pragma unroll
    for (int q = 0; q < 10; q++) {
      agg[q] = __hfma2(a0, r0.h[q], agg[q]);
      agg[q] = __hfma2(a1, r1.h[q], agg[q]);
    }
    p += 16;
  }
  if (p < end) {
    __half a0h = att[(size_t)p * NH + head];
    int sn0 = srcc[p];
    R20 r0 = ldrow20(Hin + ((size_t)sn0 * NH + head) * 20);
    __half2 a0 = __half2half2(a0h);
#pragma unroll
    for (int q = 0; q < 10; q++) agg[q] = __hfma2(a0, r0.h[q], agg[q]);
  }
#pragma unroll
  for (int q = 0; q < 10; q++) SLOTRED_H2(agg[q]);
  if (eslot == 0) {
    __half2 s2 = __float2half2_rn(invden[g] * (1.0f - ALPHA));
    __half2 al = __float2half2_rn(ALPHA);
    float o[C];
#pragma unroll
    for (int q = 0; q < 10; q++) {
      __half2 m = __hfma2(s2, agg[q], __hmul2(al, h0.h[q]));
      m = __hadd2(m, H2SWZ(m, 0x041F));
      m = __hadd2(m, H2SWZ(m, 0x081F));
      float2 f = __half22float2(m);
      o[2 * q]     = f.x * 0.25f;
      o[2 * q + 1] = f.y * 0.25f;
    }
    // distributed gate dot: partial on own 5 channels, reduce over heads
    float dotp = 0.f;
#pragma unroll
    for (int j = 0; j < 5; j++) {
      int c = head * 5 + j;
      dotp += o[c] * wsW[c];
    }
    dotp += FSWZ(dotp, 0x041F);
    dotp += FSWZ(dotp, 0x081F);
    const float gate = 1.f / (1.f + __expf(-(dotp + wsb[0])));
    const int b = gids[n];
    const int lb = b - sgmin;
    if (lb < RSPAN) {
#pragma unroll
      for (int j = 0; j < 5; j++) {
        int c = head * 5 + j;
        atomicAdd(&sacc[lb * C + c], o[c] * gate);
      }
    } else {
#pragma unroll
      for (int j = 0; j < 5; j++) {
        int c = head * 5 + j;
        atomicAdd(&out[(size_t)b * C + c], o[c] * gate);
      }
    }
  }
  __syncthreads();
  for (int i = t; i < RSPAN * C; i += 256) {
    float v = sacc[i];
    if (v != 0.f) atomicAdd(&out[(size_t)(sgmin + i / C) * C + (i - (i / C) * C)], v);
  }
}

// ---------------------------------------------------------------------------
extern "C" void kernel_launch(void* const* d_in, const int* in_sizes, int n_in,
                              void* d_out, int out_size, void* d_ws, size_t ws_size,
                              hipStream_t stream)
{
  const int*   node_ids = (const int*)  d_in[0];
  const int*   edge_src = (const int*)  d_in[1];
  const int*   edge_dst = (const int*)  d_in[2];
  const int*   graph_ids= (const int*)  d_in[3];
  const float* emb      = (const float*)d_in[4];
  const float* W1       = (const float*)d_in[5];
  const float* b1       = (const float*)d_in[6];
  const float* W2       = (const float*)d_in[7];
  const float* b2       = (const float*)d_in[8];
  const float* gat_W    = (const float*)d_in[9];
  const float* gat_asrc = (const float*)d_in[10];
  const float* gat_adst = (const float*)d_in[11];
  const float* ws_W     = (const float*)d_in[12];
  const float* ws_b     = (const float*)d_in[13];
  float* out = (float*)d_out;

  // ---- workspace (~66 MB). X region time-shared: gbuf -> att ----
  float* esf    = (float*)d_ws;                      // VPAD*NH
  float* edf    = esf   + (size_t)VPAD * NH;
  float* es     = edf   + (size_t)VPAD * NH;         // N*NH
  float* ed     = es    + (size_t)NNODE * NH;
  float* invden = ed    + (size_t)NNODE * NH;
  float* bb     = invden+ (size_t)NNODE * NH;        // 96
  float* coef   = bb + 96;                           // 96*20
  int*   offs   = (int*)(coef + 96 * C);             // N
  int*   deg    = offs + NNODE;                      // N
  int*   gcur   = deg + NNODE;                       // 300
  int*   srcc   = gcur + NBKT;                       // NSLOT
  int*   srcv   = srcc + NSLOT;                      // NSLOT
  uintptr_t a16 = ((uintptr_t)(srcv + NSLOT) + 15) & ~(uintptr_t)15;
  __half* zfull = (__half*)a16;                      // VPAD*NH*20
  __half* zb    = zfull + (size_t)VPAD * NH * 20;    // N*NH*20
  __half* bufA  = zb    + (size_t)NNODE * NH * 20;
  __half* bufB  = bufA  + (size_t)NNODE * NH * 20;
  ushort* W1t   = (ushort*)(bufB + (size_t)NNODE * NH * 20);  // 40*512*8
  ushort* Wcpt  = W1t + (size_t)40 * 512 * 8;        // 64*96*8
  uintptr_t x16 = ((uintptr_t)(Wcpt + 64 * 96 * 8) + 15) & ~(uintptr_t)15;
  int*    gbuf  = (int*)x16;                         // X: NSLOT ints
  __half* att   = (__half*)x16;                      // X: NH*NSLOT halves

  hipMemsetAsync(out, 0, (size_t)NB * C * sizeof(float), stream);
  hipMemsetAsync(gcur, 0, NBKT * sizeof(int), stream);

  // prep
  k_cvt_w1<<<(40 * 512 * 8) / 256, 256, 0, stream>>>(W1, W1t);
  k_prep_coef<<<1, 128, 0, stream>>>(gat_W, gat_asrc, gat_adst, b2, coef, bb);
  k_prep_wcp<<<(64 * 96 * 8) / 256, 256, 0, stream>>>(W2, coef, Wcpt);

  // CSR build (gapped buckets; X: gbuf)
  k_bkt_scatter<<<NEBLK, 256, 0, stream>>>(edge_src, edge_dst, gcur, gbuf);
  k_csr_build<<<NBKT, 256, 0, stream>>>(gcur, gbuf, node_ids,
                                        offs, deg, srcc, srcv);

  // MLP + folded layer-0 GAT projection (reads f32 emb directly)
  k_mlp_mfma<<<VPAD / BM, 512, 0, stream>>>(emb, W1t, b1, Wcpt, bb,
                                            zfull, esf, edf);

  const int HB = NNODE / 8;   // 9600 blocks for hop kernels (X: att)
  // layer 0 (vocab-space z); last hop fused with layer-1 projection
  k_hop_first<<<HB, 256, 0, stream>>>(offs, deg, srcv, esf, edf, node_ids,
                                      zfull, att, invden, bufA);
  k_hop_mid<<<HB, 256, 0, stream>>>(offs, deg, srcc, att, invden, bufA, zfull,
                                    node_ids, bufB);
  k_hop_last_proj<<<HB, 256, 0, stream>>>(offs, deg, srcc, att, invden, bufB,
                                          zfull, node_ids,
                                          gat_W + (size_t)NH * C * C,
                                          gat_asrc + NH * C, gat_adst + NH * C,
                                          zb, es, ed);
  // layer 1
  k_hop_first<<<HB, 256, 0, stream>>>(offs, deg, srcc, es, ed,
                                      (const int*)nullptr, zb, att, invden,
                                      bufA);
  k_hop_mid<<<HB, 256, 0, stream>>>(offs, deg, srcc, att, invden, bufA, zb,
                                    (const int*)nullptr, bufB);
  k_hop_last_final<<<HB, 256, 0, stream>>>(offs, deg, srcc, att, invden, bufB,
                                           zb, graph_ids, ws_W, ws_b, out);
}